// Round 1
// baseline (404.717 us; speedup 1.0000x reference)
//
#include <hip/hip_runtime.h>
#include <hip/hip_bf16.h>

// GraphConv layer: edge MLP (2x 128x128) + segment_sum + node MLP (256x128, 128x128)
// Strategy: bf16 MFMA (16x16x32) with f32 accumulation everywhere; f32 atomics for agg.

typedef __attribute__((ext_vector_type(4))) float f32x4;
typedef __attribute__((ext_vector_type(8))) __bf16 bf16x8;
typedef __attribute__((ext_vector_type(4))) short s16x4;

__device__ __forceinline__ short f2bf(float f) {
  // round-to-nearest-even f32 -> bf16 (inputs finite)
  unsigned x = __float_as_uint(f);
  x = (x + 0x7fffu + ((x >> 16) & 1u)) >> 16;
  return (short)x;
}

// XOR swizzle on byte bits 4..6 within a row: kills the stride-256B/512B
// same-bank pattern for 16-lane row-parallel ds_read_b128 (G4 / m214 r268).
__device__ __forceinline__ int swzB(int row, int colByte, int strideB) {
  return row * strideB + (colByte ^ ((row & 7) << 4));
}

// ---------------- prep: cast+transpose all weights to bf16 [out][in] in ws ----
__global__ void prep_kernel(const float* __restrict__ ew1, const float* __restrict__ ew2,
                            const float* __restrict__ nw1, const float* __restrict__ nw2,
                            short* __restrict__ wsS) {
  int idx = blockIdx.x * 256 + threadIdx.x;
  if (idx < 16384) {                       // W1t [128n][128k]
    int n = idx >> 7, k = idx & 127;
    wsS[idx] = f2bf(ew1[k * 128 + n]);
  } else if (idx < 32768) {                // W2t
    int o = idx - 16384; int n = o >> 7, k = o & 127;
    wsS[idx] = f2bf(ew2[k * 128 + n]);
  } else if (idx < 65536) {                // NW1t [128n][256k]
    int o = idx - 32768; int n = o >> 8, k = o & 255;
    wsS[idx] = f2bf(nw1[k * 128 + n]);
  } else if (idx < 81920) {                // NW2t [128n][128k]
    int o = idx - 65536; int n = o >> 7, k = o & 127;
    wsS[idx] = f2bf(nw2[k * 128 + n]);
  }
}

// ---------------- edge kernel: e = MLP(h[row]-h[col]); agg[row] += e ---------
__global__ __launch_bounds__(512) void edge_kernel(
    const float* __restrict__ h, const int* __restrict__ ei,
    const float* __restrict__ b1, const float* __restrict__ b2,
    const short* __restrict__ W1t, const short* __restrict__ W2t,
    float* __restrict__ agg, int nE) {
  __shared__ __align__(16) char sW1[32768];   // W1t bf16 [128][128] swizzled
  __shared__ __align__(16) char sW2[32768];
  __shared__ __align__(16) char sX[32768];    // diff tile [128 edges][128]
  __shared__ __align__(16) char sT[32768];    // relu(layer1) tile

  const int tid = threadIdx.x;
  const int lane = tid & 63, wv = tid >> 6;
  const int lr = lane & 15, grp = lane >> 4;
  const int eb = blockIdx.x * 128;
  const int* rowI = ei;        // edge_index[0][:]
  const int* colI = ei + nE;   // edge_index[1][:]

  // stage weights (already transposed bf16 in ws) -> LDS, swizzled
#pragma unroll
  for (int i = 0; i < 4; ++i) {
    int c = i * 512 + tid;                 // 16B chunk id, 2048 per matrix
    int n = c >> 4, kB = (c & 15) * 16;
    *(int4*)(sW1 + swzB(n, kB, 256)) = ((const int4*)W1t)[c];
    *(int4*)(sW2 + swzB(n, kB, 256)) = ((const int4*)W2t)[c];
  }
  // gather diff = h[row]-h[col] -> bf16 -> sX   (4 threads per edge)
  {
    int lrow = tid >> 2;
    int e = eb + lrow;
    int r = 0, cidx = 0;
    if (e < nE) { r = rowI[e]; cidx = colI[e]; }   // OOB: h[0]-h[0]=0
    const f32x4* hr = (const f32x4*)(h + (long)r * 128);
    const f32x4* hc = (const f32x4*)(h + (long)cidx * 128);
#pragma unroll
    for (int it = 0; it < 8; ++it) {
      int c4 = (tid & 3) + it * 4;         // float4 index in row (coalesced 64B/4 lanes)
      f32x4 a = hr[c4], b = hc[c4];
      s16x4 p;
      p.x = f2bf(a.x - b.x); p.y = f2bf(a.y - b.y);
      p.z = f2bf(a.z - b.z); p.w = f2bf(a.w - b.w);
      *(s16x4*)(sX + swzB(lrow, c4 * 8, 256)) = p;
    }
  }
  __syncthreads();

  // layer 1: wave wv computes rows [wv*16, wv*16+16) x all 128 cols
  f32x4 acc[8];
#pragma unroll
  for (int j = 0; j < 8; ++j) acc[j] = (f32x4){0.f, 0.f, 0.f, 0.f};
#pragma unroll
  for (int kk = 0; kk < 4; ++kk) {
    int kB = (kk * 32 + grp * 8) * 2;
    bf16x8 a = *(const bf16x8*)(sX + swzB(wv * 16 + lr, kB, 256));
#pragma unroll
    for (int j = 0; j < 8; ++j) {
      bf16x8 b = *(const bf16x8*)(sW1 + swzB(j * 16 + lr, kB, 256));
      acc[j] = __builtin_amdgcn_mfma_f32_16x16x32_bf16(a, b, acc[j], 0, 0, 0);
    }
  }
  // bias + relu -> sT (bf16)
#pragma unroll
  for (int j = 0; j < 8; ++j) {
    int col = j * 16 + lr;
    float bv = b1[col];
#pragma unroll
    for (int r = 0; r < 4; ++r) {
      int row = wv * 16 + grp * 4 + r;
      float v = acc[j][r] + bv;
      v = v > 0.f ? v : 0.f;
      *(short*)(sT + swzB(row, col * 2, 256)) = f2bf(v);
    }
  }
  __syncthreads();

  // layer 2
  f32x4 acc2[8];
#pragma unroll
  for (int j = 0; j < 8; ++j) acc2[j] = (f32x4){0.f, 0.f, 0.f, 0.f};
#pragma unroll
  for (int kk = 0; kk < 4; ++kk) {
    int kB = (kk * 32 + grp * 8) * 2;
    bf16x8 a = *(const bf16x8*)(sT + swzB(wv * 16 + lr, kB, 256));
#pragma unroll
    for (int j = 0; j < 8; ++j) {
      bf16x8 b = *(const bf16x8*)(sW2 + swzB(j * 16 + lr, kB, 256));
      acc2[j] = __builtin_amdgcn_mfma_f32_16x16x32_bf16(a, b, acc2[j], 0, 0, 0);
    }
  }
  // epilogue: agg[row[e]] += e_out  (f32 atomics)
  int nd[4]; bool okr[4];
#pragma unroll
  for (int r = 0; r < 4; ++r) {
    int e = eb + wv * 16 + grp * 4 + r;
    okr[r] = e < nE;
    nd[r] = okr[r] ? rowI[e] : 0;
  }
#pragma unroll
  for (int j = 0; j < 8; ++j) {
    int col = j * 16 + lr;
    float bv = b2[col];
#pragma unroll
    for (int r = 0; r < 4; ++r) {
      if (okr[r]) atomicAdd(agg + (long)nd[r] * 128 + col, acc2[j][r] + bv);
    }
  }
}

// ---------------- node kernel: out = MLP(concat(h, agg)) (in-place on d_out) --
__global__ __launch_bounds__(512) void node_kernel(
    const float* __restrict__ h, const float* agg,   // agg aliases out!
    const float* __restrict__ b1, const float* __restrict__ b2,
    const short* __restrict__ W1t, const short* __restrict__ W2t,
    float* out, int nN) {
  __shared__ __align__(16) char sZ[32768];    // z tile [64][256] bf16
  __shared__ __align__(16) char sW1[65536];   // NW1t [128n][256k]
  __shared__ __align__(16) char sW2[32768];   // NW2t [128n][128k]
  __shared__ __align__(16) char sT[16384];    // [64][128]

  const int tid = threadIdx.x;
  const int lane = tid & 63, wv = tid >> 6;
  const int lr = lane & 15, grp = lane >> 4;
  const int nb = blockIdx.x * 64;

#pragma unroll
  for (int i = 0; i < 8; ++i) {
    int c = i * 512 + tid;                    // 4096 chunks
    int n = c >> 5, kB = (c & 31) * 16;
    *(int4*)(sW1 + swzB(n, kB, 512)) = ((const int4*)W1t)[c];
  }
#pragma unroll
  for (int i = 0; i < 4; ++i) {
    int c = i * 512 + tid;                    // 2048 chunks
    int n = c >> 4, kB = (c & 15) * 16;
    *(int4*)(sW2 + swzB(n, kB, 256)) = ((const int4*)W2t)[c];
  }
  // gather z = [h | agg] -> bf16 -> sZ  (8 threads per row)
  {
    int i = tid >> 3;
    int node = nb + i;
    bool ok = node < nN;
    int nd = ok ? node : 0;
#pragma unroll
    for (int it = 0; it < 8; ++it) {
      int c4 = (tid & 7) + it * 8;            // float4 idx 0..63 within 256 cols
      int col = c4 * 4;
      f32x4 v;
      if (col < 128) v = *(const f32x4*)(h + (long)nd * 128 + col);
      else           v = *(const f32x4*)(agg + (long)nd * 128 + (col - 128));
      if (!ok) v = (f32x4){0.f, 0.f, 0.f, 0.f};
      s16x4 p;
      p.x = f2bf(v.x); p.y = f2bf(v.y); p.z = f2bf(v.z); p.w = f2bf(v.w);
      *(s16x4*)(sZ + swzB(i, col * 2, 512)) = p;
    }
  }
  __syncthreads();

  // layer 1: wave tile 16 rows x 64 cols; K=256
  const int r0 = (wv >> 1) * 16;
  const int cb = (wv & 1) * 64;
  f32x4 acc[4];
#pragma unroll
  for (int j = 0; j < 4; ++j) acc[j] = (f32x4){0.f, 0.f, 0.f, 0.f};
#pragma unroll
  for (int kk = 0; kk < 8; ++kk) {
    int kB = (kk * 32 + grp * 8) * 2;
    bf16x8 a = *(const bf16x8*)(sZ + swzB(r0 + lr, kB, 512));
#pragma unroll
    for (int j = 0; j < 4; ++j) {
      bf16x8 b = *(const bf16x8*)(sW1 + swzB(cb + j * 16 + lr, kB, 512));
      acc[j] = __builtin_amdgcn_mfma_f32_16x16x32_bf16(a, b, acc[j], 0, 0, 0);
    }
  }
#pragma unroll
  for (int j = 0; j < 4; ++j) {
    int col = cb + j * 16 + lr;
    float bv = b1[col];
#pragma unroll
    for (int r = 0; r < 4; ++r) {
      int row = r0 + grp * 4 + r;
      float v = acc[j][r] + bv;
      v = v > 0.f ? v : 0.f;
      *(short*)(sT + swzB(row, col * 2, 256)) = f2bf(v);
    }
  }
  __syncthreads();

  // layer 2: K=128
  f32x4 acc2[4];
#pragma unroll
  for (int j = 0; j < 4; ++j) acc2[j] = (f32x4){0.f, 0.f, 0.f, 0.f};
#pragma unroll
  for (int kk = 0; kk < 4; ++kk) {
    int kB = (kk * 32 + grp * 8) * 2;
    bf16x8 a = *(const bf16x8*)(sT + swzB(r0 + lr, kB, 256));
#pragma unroll
    for (int j = 0; j < 4; ++j) {
      bf16x8 b = *(const bf16x8*)(sW2 + swzB(cb + j * 16 + lr, kB, 256));
      acc2[j] = __builtin_amdgcn_mfma_f32_16x16x32_bf16(a, b, acc2[j], 0, 0, 0);
    }
  }
#pragma unroll
  for (int j = 0; j < 4; ++j) {
    int col = cb + j * 16 + lr;
    float bv = b2[col];
#pragma unroll
    for (int r = 0; r < 4; ++r) {
      int node = nb + r0 + grp * 4 + r;
      if (node < nN) out[(long)node * 128 + col] = acc2[j][r] + bv;
    }
  }
}

extern "C" void kernel_launch(void* const* d_in, const int* in_sizes, int n_in,
                              void* d_out, int out_size, void* d_ws, size_t ws_size,
                              hipStream_t stream) {
  const float* h   = (const float*)d_in[0];
  const int*   ei  = (const int*)d_in[1];
  const float* ew1 = (const float*)d_in[2];
  const float* eb1 = (const float*)d_in[3];
  const float* ew2 = (const float*)d_in[4];
  const float* eb2 = (const float*)d_in[5];
  const float* nw1 = (const float*)d_in[6];
  const float* nb1 = (const float*)d_in[7];
  const float* nw2 = (const float*)d_in[8];
  const float* nb2 = (const float*)d_in[9];
  float* out = (float*)d_out;

  const int E = in_sizes[1] / 2;     // 600000
  const int N = in_sizes[0] / 128;   // 50000

  short* wsS  = (short*)d_ws;        // bf16 transposed weights, 160KB total
  short* W1t  = wsS;
  short* W2t  = wsS + 16384;
  short* NW1t = wsS + 32768;
  short* NW2t = wsS + 65536;

  // d_out doubles as the f32 agg accumulator; zero it every call (deterministic).
  hipMemsetAsync(d_out, 0, (size_t)out_size * sizeof(float), stream);
  prep_kernel<<<320, 256, 0, stream>>>(ew1, ew2, nw1, nw2, wsS);
  edge_kernel<<<(E + 127) / 128, 512, 0, stream>>>(h, ei, eb1, eb2, W1t, W2t, out, E);
  node_kernel<<<(N + 63) / 64, 512, 0, stream>>>(h, out, nb1, nb2, NW1t, NW2t, out, N);
}

// Round 3
// 227.323 us; speedup vs baseline: 1.7804x; 1.7804x over previous
//
#include <hip/hip_runtime.h>
#include <hip/hip_bf16.h>

// GraphConv layer: edge MLP (2x 128x128) + segment_sum + node MLP (256x128, 128x128)
// R2 (resubmit after infra failure): on-device CSR sort of edges by destination row ->
// segmented-reduce epilogue (12x fewer f32 atomics), edge kernel at 64.5KB LDS -> 2 blocks/CU.

typedef __attribute__((ext_vector_type(4))) float f32x4;
typedef __attribute__((ext_vector_type(8))) __bf16 bf16x8;
typedef __attribute__((ext_vector_type(4))) short s16x4;

__device__ __forceinline__ short f2bf(float f) {
  unsigned x = __float_as_uint(f);
  x = (x + 0x7fffu + ((x >> 16) & 1u)) >> 16;
  return (short)x;
}

// XOR swizzle on byte bits 4..6 within a row (G4 / m214 r268)
__device__ __forceinline__ int swzB(int row, int colByte, int strideB) {
  return row * strideB + (colByte ^ ((row & 7) << 4));
}

// ---------------- prep: cast+transpose all weights to bf16 [out][in] in ws ----
__global__ void prep_kernel(const float* __restrict__ ew1, const float* __restrict__ ew2,
                            const float* __restrict__ nw1, const float* __restrict__ nw2,
                            short* __restrict__ wsS) {
  int idx = blockIdx.x * 256 + threadIdx.x;
  if (idx < 16384) {                       // W1t [128n][128k]
    int n = idx >> 7, k = idx & 127;
    wsS[idx] = f2bf(ew1[k * 128 + n]);
  } else if (idx < 32768) {                // W2t
    int o = idx - 16384; int n = o >> 7, k = o & 127;
    wsS[idx] = f2bf(ew2[k * 128 + n]);
  } else if (idx < 65536) {                // NW1t [128n][256k]
    int o = idx - 32768; int n = o >> 8, k = o & 255;
    wsS[idx] = f2bf(nw1[k * 128 + n]);
  } else if (idx < 81920) {                // NW2t [128n][128k]
    int o = idx - 65536; int n = o >> 7, k = o & 127;
    wsS[idx] = f2bf(nw2[k * 128 + n]);
  }
}

// ---------------- CSR build ----------------
__global__ void hist_kernel(const int* __restrict__ rowI, int* __restrict__ deg, int nE) {
  int e = blockIdx.x * 256 + threadIdx.x;
  if (e < nE) atomicAdd(&deg[rowI[e]], 1);
}

// per-256-chunk exclusive scan; cursor[g] = local exclusive, bsums[b] = chunk total
__global__ void scan_local_kernel(const int* __restrict__ deg, int* __restrict__ cursor,
                                  int* __restrict__ bsums) {
  __shared__ int s[256];
  int i = threadIdx.x, g = blockIdx.x * 256 + i;
  int v = deg[g];
  s[i] = v; __syncthreads();
#pragma unroll
  for (int off = 1; off < 256; off <<= 1) {
    int t = (i >= off) ? s[i - off] : 0;
    __syncthreads();
    s[i] += t;
    __syncthreads();
  }
  cursor[g] = s[i] - v;
  if (i == 255) bsums[blockIdx.x] = s[255];
}

__global__ void scan_blocks_kernel(int* __restrict__ bsums, int nb) {
  __shared__ int s[256];
  int i = threadIdx.x;
  int v = (i < nb) ? bsums[i] : 0;
  s[i] = v; __syncthreads();
#pragma unroll
  for (int off = 1; off < 256; off <<= 1) {
    int t = (i >= off) ? s[i - off] : 0;
    __syncthreads();
    s[i] += t;
    __syncthreads();
  }
  if (i < nb) bsums[i] = s[i] - v;
}

__global__ void finalize_kernel(int* __restrict__ cursor, const int* __restrict__ bsums) {
  int i = blockIdx.x * 256 + threadIdx.x;
  cursor[i] += bsums[i >> 8];
}

__global__ void scatter_kernel(const int* __restrict__ ei, int* __restrict__ cursor,
                               int* __restrict__ rowS, int* __restrict__ colS, int nE) {
  int e = blockIdx.x * 256 + threadIdx.x;
  if (e < nE) {
    int r = ei[e];
    int pos = atomicAdd(&cursor[r], 1);
    rowS[pos] = r;
    colS[pos] = ei[nE + e];
  }
}

// ---------------- edge kernel (CSR-sorted): e = MLP(h[r]-h[c]); seg-reduce -> agg ----
__global__ __launch_bounds__(512, 4) void edge_csr_kernel(
    const float* __restrict__ h, const int* __restrict__ rowS, const int* __restrict__ colS,
    const float* __restrict__ b1, const float* __restrict__ b2,
    const short* __restrict__ W1t, const short* __restrict__ W2t,
    float* __restrict__ agg, int nE) {
  __shared__ __align__(16) char sm[65536];
  __shared__ int rs[128];
  char* sW = sm;                    // 32KB: W1 then re-staged W2 (swizzled bf16 [128][128])
  char* sT = sm + 32768;            // 32KB: relu(layer1) bf16 [128][128]
  float* stg = (float*)sm;          // 64KB: f32 [128][128] epilogue stage (overlays both)

  const int tid = threadIdx.x;
  const int lane = tid & 63, wv = tid >> 6;
  const int lr = lane & 15, grp = lane >> 4;
  const int eb = blockIdx.x * 128;

  if (tid < 128) rs[tid] = (eb + tid < nE) ? rowS[eb + tid] : -1;

  // stage W1 -> sW (2048 x 16B chunks)
#pragma unroll
  for (int i = 0; i < 4; ++i) {
    int c = i * 512 + tid;
    int n = c >> 4, kB = (c & 15) * 16;
    *(int4*)(sW + swzB(n, kB, 256)) = ((const int4*)W1t)[c];
  }

  // gather diff directly into A fragments (sorted rows -> near-uniform h[r] loads)
  bf16x8 afr[4];
  {
    int slot = eb + wv * 16 + lr;
    int r = 0, cc = 0;
    if (slot < nE) { r = rowS[slot]; cc = colS[slot]; }
    const float* hr = h + (long)r * 128;
    const float* hc = h + (long)cc * 128;
#pragma unroll
    for (int kk = 0; kk < 4; ++kk) {
      int k0 = kk * 32 + grp * 8;
      f32x4 a0 = *(const f32x4*)(hr + k0), a1 = *(const f32x4*)(hr + k0 + 4);
      f32x4 c0 = *(const f32x4*)(hc + k0), c1 = *(const f32x4*)(hc + k0 + 4);
      union { bf16x8 v; short s[8]; } u;
      u.s[0] = f2bf(a0.x - c0.x); u.s[1] = f2bf(a0.y - c0.y);
      u.s[2] = f2bf(a0.z - c0.z); u.s[3] = f2bf(a0.w - c0.w);
      u.s[4] = f2bf(a1.x - c1.x); u.s[5] = f2bf(a1.y - c1.y);
      u.s[6] = f2bf(a1.z - c1.z); u.s[7] = f2bf(a1.w - c1.w);
      afr[kk] = u.v;
    }
  }
  __syncthreads();

  // layer 1: wave wv -> rows [wv*16, wv*16+16) x 128 cols
  f32x4 acc[8];
#pragma unroll
  for (int j = 0; j < 8; ++j) acc[j] = (f32x4){0.f, 0.f, 0.f, 0.f};
#pragma unroll
  for (int kk = 0; kk < 4; ++kk) {
    int kB = (kk * 32 + grp * 8) * 2;
#pragma unroll
    for (int j = 0; j < 8; ++j) {
      bf16x8 b = *(const bf16x8*)(sW + swzB(j * 16 + lr, kB, 256));
      acc[j] = __builtin_amdgcn_mfma_f32_16x16x32_bf16(afr[kk], b, acc[j], 0, 0, 0);
    }
  }
  // bias + relu -> sT (bf16)
#pragma unroll
  for (int j = 0; j < 8; ++j) {
    int col = j * 16 + lr;
    float bv = b1[col];
#pragma unroll
    for (int r = 0; r < 4; ++r) {
      int row = wv * 16 + grp * 4 + r;
      float v = acc[j][r] + bv;
      v = v > 0.f ? v : 0.f;
      *(short*)(sT + swzB(row, col * 2, 256)) = f2bf(v);
    }
  }
  __syncthreads();   // all W1 reads + sT writes done

  // re-stage W2 over sW
#pragma unroll
  for (int i = 0; i < 4; ++i) {
    int c = i * 512 + tid;
    int n = c >> 4, kB = (c & 15) * 16;
    *(int4*)(sW + swzB(n, kB, 256)) = ((const int4*)W2t)[c];
  }
  __syncthreads();

  // layer 2 (+bias2, since agg sums per-edge e = ... + b2)
  f32x4 acc2[8];
#pragma unroll
  for (int j = 0; j < 8; ++j) acc2[j] = (f32x4){0.f, 0.f, 0.f, 0.f};
#pragma unroll
  for (int kk = 0; kk < 4; ++kk) {
    int kB = (kk * 32 + grp * 8) * 2;
    bf16x8 a = *(const bf16x8*)(sT + swzB(wv * 16 + lr, kB, 256));
#pragma unroll
    for (int j = 0; j < 8; ++j) {
      bf16x8 b = *(const bf16x8*)(sW + swzB(j * 16 + lr, kB, 256));
      acc2[j] = __builtin_amdgcn_mfma_f32_16x16x32_bf16(a, b, acc2[j], 0, 0, 0);
    }
  }
  __syncthreads();   // all sT/sW reads done -> safe to overlay stg

  // write f32 stage (bias2 added); rows = sorted edge slots
#pragma unroll
  for (int j = 0; j < 8; ++j) {
    int col = j * 16 + lr;
    float bv = b2[col];
#pragma unroll
    for (int r = 0; r < 4; ++r) {
      int row = wv * 16 + grp * 4 + r;
      *(float*)((char*)stg + row * 512 + ((col * 4) ^ ((row & 7) << 4))) = acc2[j][r] + bv;
    }
  }
  __syncthreads();

  // segmented reduce: thread (col c, chunk q) walks 32 sorted rows, flushes per segment
  {
    int c = tid & 127, q = tid >> 7;
    float run = 0.f;
    int cur = rs[q * 32];
    for (int i = 0; i < 32; ++i) {
      int row = q * 32 + i;
      int rr = rs[row];
      float v = *(const float*)((const char*)stg + row * 512 + ((c * 4) ^ ((row & 7) << 4)));
      if (rr != cur) {
        if (cur >= 0) atomicAdd(agg + (long)cur * 128 + c, run);
        run = 0.f; cur = rr;
      }
      run += v;
    }
    if (cur >= 0) atomicAdd(agg + (long)cur * 128 + c, run);
  }
}

// ---------------- R1 fallback edge kernel (per-edge atomics) ----------------
__global__ __launch_bounds__(512) void edge_kernel(
    const float* __restrict__ h, const int* __restrict__ ei,
    const float* __restrict__ b1, const float* __restrict__ b2,
    const short* __restrict__ W1t, const short* __restrict__ W2t,
    float* __restrict__ agg, int nE) {
  __shared__ __align__(16) char sW1[32768];
  __shared__ __align__(16) char sW2[32768];
  __shared__ __align__(16) char sX[32768];
  __shared__ __align__(16) char sT[32768];

  const int tid = threadIdx.x;
  const int lane = tid & 63, wv = tid >> 6;
  const int lr = lane & 15, grp = lane >> 4;
  const int eb = blockIdx.x * 128;
  const int* rowI = ei;
  const int* colI = ei + nE;

#pragma unroll
  for (int i = 0; i < 4; ++i) {
    int c = i * 512 + tid;
    int n = c >> 4, kB = (c & 15) * 16;
    *(int4*)(sW1 + swzB(n, kB, 256)) = ((const int4*)W1t)[c];
    *(int4*)(sW2 + swzB(n, kB, 256)) = ((const int4*)W2t)[c];
  }
  {
    int lrow = tid >> 2;
    int e = eb + lrow;
    int r = 0, cidx = 0;
    if (e < nE) { r = rowI[e]; cidx = colI[e]; }
    const f32x4* hr = (const f32x4*)(h + (long)r * 128);
    const f32x4* hc = (const f32x4*)(h + (long)cidx * 128);
#pragma unroll
    for (int it = 0; it < 8; ++it) {
      int c4 = (tid & 3) + it * 4;
      f32x4 a = hr[c4], b = hc[c4];
      s16x4 p;
      p.x = f2bf(a.x - b.x); p.y = f2bf(a.y - b.y);
      p.z = f2bf(a.z - b.z); p.w = f2bf(a.w - b.w);
      *(s16x4*)(sX + swzB(lrow, c4 * 8, 256)) = p;
    }
  }
  __syncthreads();

  f32x4 acc[8];
#pragma unroll
  for (int j = 0; j < 8; ++j) acc[j] = (f32x4){0.f, 0.f, 0.f, 0.f};
#pragma unroll
  for (int kk = 0; kk < 4; ++kk) {
    int kB = (kk * 32 + grp * 8) * 2;
    bf16x8 a = *(const bf16x8*)(sX + swzB(wv * 16 + lr, kB, 256));
#pragma unroll
    for (int j = 0; j < 8; ++j) {
      bf16x8 b = *(const bf16x8*)(sW1 + swzB(j * 16 + lr, kB, 256));
      acc[j] = __builtin_amdgcn_mfma_f32_16x16x32_bf16(a, b, acc[j], 0, 0, 0);
    }
  }
#pragma unroll
  for (int j = 0; j < 8; ++j) {
    int col = j * 16 + lr;
    float bv = b1[col];
#pragma unroll
    for (int r = 0; r < 4; ++r) {
      int row = wv * 16 + grp * 4 + r;
      float v = acc[j][r] + bv;
      v = v > 0.f ? v : 0.f;
      *(short*)(sT + swzB(row, col * 2, 256)) = f2bf(v);
    }
  }
  __syncthreads();

  f32x4 acc2[8];
#pragma unroll
  for (int j = 0; j < 8; ++j) acc2[j] = (f32x4){0.f, 0.f, 0.f, 0.f};
#pragma unroll
  for (int kk = 0; kk < 4; ++kk) {
    int kB = (kk * 32 + grp * 8) * 2;
    bf16x8 a = *(const bf16x8*)(sT + swzB(wv * 16 + lr, kB, 256));
#pragma unroll
    for (int j = 0; j < 8; ++j) {
      bf16x8 b = *(const bf16x8*)(sW2 + swzB(j * 16 + lr, kB, 256));
      acc2[j] = __builtin_amdgcn_mfma_f32_16x16x32_bf16(a, b, acc2[j], 0, 0, 0);
    }
  }
  int nd[4]; bool okr[4];
#pragma unroll
  for (int r = 0; r < 4; ++r) {
    int e = eb + wv * 16 + grp * 4 + r;
    okr[r] = e < nE;
    nd[r] = okr[r] ? rowI[e] : 0;
  }
#pragma unroll
  for (int j = 0; j < 8; ++j) {
    int col = j * 16 + lr;
    float bv = b2[col];
#pragma unroll
    for (int r = 0; r < 4; ++r) {
      if (okr[r]) atomicAdd(agg + (long)nd[r] * 128 + col, acc2[j][r] + bv);
    }
  }
}

// ---------------- node kernel: out = MLP(concat(h, agg)) (in-place on d_out) --
__global__ __launch_bounds__(512) void node_kernel(
    const float* __restrict__ h, const float* agg,   // agg aliases out!
    const float* __restrict__ b1, const float* __restrict__ b2,
    const short* __restrict__ W1t, const short* __restrict__ W2t,
    float* out, int nN) {
  __shared__ __align__(16) char sZ[32768];
  __shared__ __align__(16) char sW1[65536];
  __shared__ __align__(16) char sW2[32768];
  __shared__ __align__(16) char sT[16384];

  const int tid = threadIdx.x;
  const int lane = tid & 63, wv = tid >> 6;
  const int lr = lane & 15, grp = lane >> 4;
  const int nb = blockIdx.x * 64;

#pragma unroll
  for (int i = 0; i < 8; ++i) {
    int c = i * 512 + tid;
    int n = c >> 5, kB = (c & 31) * 16;
    *(int4*)(sW1 + swzB(n, kB, 512)) = ((const int4*)W1t)[c];
  }
#pragma unroll
  for (int i = 0; i < 4; ++i) {
    int c = i * 512 + tid;
    int n = c >> 4, kB = (c & 15) * 16;
    *(int4*)(sW2 + swzB(n, kB, 256)) = ((const int4*)W2t)[c];
  }
  {
    int i = tid >> 3;
    int node = nb + i;
    bool ok = node < nN;
    int nd = ok ? node : 0;
#pragma unroll
    for (int it = 0; it < 8; ++it) {
      int c4 = (tid & 7) + it * 8;
      int col = c4 * 4;
      f32x4 v;
      if (col < 128) v = *(const f32x4*)(h + (long)nd * 128 + col);
      else           v = *(const f32x4*)(agg + (long)nd * 128 + (col - 128));
      if (!ok) v = (f32x4){0.f, 0.f, 0.f, 0.f};
      s16x4 p;
      p.x = f2bf(v.x); p.y = f2bf(v.y); p.z = f2bf(v.z); p.w = f2bf(v.w);
      *(s16x4*)(sZ + swzB(i, col * 2, 512)) = p;
    }
  }
  __syncthreads();

  const int r0 = (wv >> 1) * 16;
  const int cb = (wv & 1) * 64;
  f32x4 acc[4];
#pragma unroll
  for (int j = 0; j < 4; ++j) acc[j] = (f32x4){0.f, 0.f, 0.f, 0.f};
#pragma unroll
  for (int kk = 0; kk < 8; ++kk) {
    int kB = (kk * 32 + grp * 8) * 2;
    bf16x8 a = *(const bf16x8*)(sZ + swzB(r0 + lr, kB, 512));
#pragma unroll
    for (int j = 0; j < 4; ++j) {
      bf16x8 b = *(const bf16x8*)(sW1 + swzB(cb + j * 16 + lr, kB, 512));
      acc[j] = __builtin_amdgcn_mfma_f32_16x16x32_bf16(a, b, acc[j], 0, 0, 0);
    }
  }
#pragma unroll
  for (int j = 0; j < 4; ++j) {
    int col = cb + j * 16 + lr;
    float bv = b1[col];
#pragma unroll
    for (int r = 0; r < 4; ++r) {
      int row = r0 + grp * 4 + r;
      float v = acc[j][r] + bv;
      v = v > 0.f ? v : 0.f;
      *(short*)(sT + swzB(row, col * 2, 256)) = f2bf(v);
    }
  }
  __syncthreads();

  f32x4 acc2[4];
#pragma unroll
  for (int j = 0; j < 4; ++j) acc2[j] = (f32x4){0.f, 0.f, 0.f, 0.f};
#pragma unroll
  for (int kk = 0; kk < 4; ++kk) {
    int kB = (kk * 32 + grp * 8) * 2;
    bf16x8 a = *(const bf16x8*)(sT + swzB(r0 + lr, kB, 256));
#pragma unroll
    for (int j = 0; j < 4; ++j) {
      bf16x8 b = *(const bf16x8*)(sW2 + swzB(cb + j * 16 + lr, kB, 256));
      acc2[j] = __builtin_amdgcn_mfma_f32_16x16x32_bf16(a, b, acc2[j], 0, 0, 0);
    }
  }
#pragma unroll
  for (int j = 0; j < 4; ++j) {
    int col = cb + j * 16 + lr;
    float bv = b2[col];
#pragma unroll
    for (int r = 0; r < 4; ++r) {
      int node = nb + r0 + grp * 4 + r;
      if (node < nN) out[(long)node * 128 + col] = acc2[j][r] + bv;
    }
  }
}

extern "C" void kernel_launch(void* const* d_in, const int* in_sizes, int n_in,
                              void* d_out, int out_size, void* d_ws, size_t ws_size,
                              hipStream_t stream) {
  const float* h   = (const float*)d_in[0];
  const int*   ei  = (const int*)d_in[1];
  const float* ew1 = (const float*)d_in[2];
  const float* eb1 = (const float*)d_in[3];
  const float* ew2 = (const float*)d_in[4];
  const float* eb2 = (const float*)d_in[5];
  const float* nw1 = (const float*)d_in[6];
  const float* nb1 = (const float*)d_in[7];
  const float* nw2 = (const float*)d_in[8];
  const float* nb2 = (const float*)d_in[9];
  float* out = (float*)d_out;

  const int E = in_sizes[1] / 2;     // 600000
  const int N = in_sizes[0] / 128;   // 50000
  const int NP = ((N + 255) / 256) * 256;   // 50176 padded
  const int NB = NP / 256;                  // 196

  short* wsS  = (short*)d_ws;        // bf16 transposed weights, 160KB
  short* W1t  = wsS;
  short* W2t  = wsS + 16384;
  short* NW1t = wsS + 32768;
  short* NW2t = wsS + 65536;

  int* deg    = (int*)(wsS + 81920);
  int* cursor = deg + NP;
  int* bsums  = cursor + NP;
  int* rowS   = bsums + 256;
  int* colS   = rowS + ((E + 63) & ~63);
  size_t needed = (size_t)((char*)(colS + E) - (char*)d_ws);

  // d_out doubles as the f32 agg accumulator; zero it every call.
  hipMemsetAsync(d_out, 0, (size_t)out_size * sizeof(float), stream);
  prep_kernel<<<320, 256, 0, stream>>>(ew1, ew2, nw1, nw2, wsS);

  if (ws_size >= needed) {
    // CSR path
    hipMemsetAsync(deg, 0, (size_t)(2 * NP + 256) * sizeof(int), stream);
    hist_kernel<<<(E + 255) / 256, 256, 0, stream>>>(ei, deg, E);
    scan_local_kernel<<<NB, 256, 0, stream>>>(deg, cursor, bsums);
    scan_blocks_kernel<<<1, 256, 0, stream>>>(bsums, NB);
    finalize_kernel<<<NB, 256, 0, stream>>>(cursor, bsums);
    scatter_kernel<<<(E + 255) / 256, 256, 0, stream>>>(ei, cursor, rowS, colS, E);
    edge_csr_kernel<<<(E + 127) / 128, 512, 0, stream>>>(h, rowS, colS, eb1, eb2,
                                                         W1t, W2t, out, E);
  } else {
    // fallback: per-edge atomics
    edge_kernel<<<(E + 127) / 128, 512, 0, stream>>>(h, ei, eb1, eb2, W1t, W2t, out, E);
  }
  node_kernel<<<(N + 63) / 64, 512, 0, stream>>>(h, out, nb1, nb2, NW1t, NW2t, out, N);
}

// Round 4
// 156.505 us; speedup vs baseline: 2.5860x; 1.4525x over previous
//
#include <hip/hip_runtime.h>
#include <hip/hip_bf16.h>

// GraphConv layer: edge MLP (2x 128x128) + segment_sum + node MLP (256x128, 128x128)
// R4: algebraic restructure.
//   g = h@e_w1 (bf16, per node).  s_e = g[row]-g[col]+b1 (linearity of layer 1).
//   T[n] = sum_e relu(s_e)  (aggregate BEFORE layer 2; pure VALU, no per-edge GEMM).
//   agg = T@e_w2 + deg*e_b2 folded into node MLP: z@n_w1 = h@A + T@(e_w2@B) + deg*(e_b2@B).
//   Per-edge MFMA: 39.3 GF -> 0.  Fallback to R3 CSR path if ws too small.

typedef __attribute__((ext_vector_type(4))) float f32x4;
typedef __attribute__((ext_vector_type(8))) __bf16 bf16x8;
typedef __attribute__((ext_vector_type(4))) short s16x4;
typedef __attribute__((ext_vector_type(8))) unsigned short u16x8;

__device__ __forceinline__ short f2bf(float f) {
  unsigned x = __float_as_uint(f);
  x = (x + 0x7fffu + ((x >> 16) & 1u)) >> 16;
  return (short)x;
}
__device__ __forceinline__ float bf2f(unsigned short u) {
  return __uint_as_float(((unsigned)u) << 16);
}
// XOR swizzle on byte bits 4..6 within a row (G4 / m214 r268)
__device__ __forceinline__ int swzB(int row, int colByte, int strideB) {
  return row * strideB + (colByte ^ ((row & 7) << 4));
}

// ================= new-path prep =================
// W1t [128o][128k] <- e_w1 ; NW1t [128o][256k] first half <- n_w1[:128] ; NW2t <- n_w2
__global__ void prep_new(const float* __restrict__ ew1, const float* __restrict__ nw1,
                         const float* __restrict__ nw2, short* __restrict__ W1t,
                         short* __restrict__ NW1t, short* __restrict__ NW2t) {
  int idx = blockIdx.x * 256 + threadIdx.x;
  if (idx < 16384) {
    int n = idx >> 7, k = idx & 127;
    W1t[idx] = f2bf(ew1[k * 128 + n]);
  } else if (idx < 32768) {
    int o = idx - 16384; int n = o >> 7, k = o & 127;
    NW1t[n * 256 + k] = f2bf(nw1[k * 128 + n]);
  } else if (idx < 49152) {
    int o = idx - 32768; int n = o >> 7, k = o & 127;
    NW2t[o] = f2bf(nw2[k * 128 + n]);
  }
}

// WB[kt][o] = sum_m e_w2[kt][m]*n_w1[128+m][o]  -> NW1t second half (k=128+kt)
// c0[o]    = sum_m e_b2[m]   *n_w1[128+m][o]
__global__ void wb_kernel(const float* __restrict__ ew2, const float* __restrict__ eb2,
                          const float* __restrict__ nw1, short* __restrict__ NW1t,
                          float* __restrict__ c0) {
  int idx = blockIdx.x * 256 + threadIdx.x;
  if (idx < 16384) {
    int o = idx & 127, kt = idx >> 7;
    float s = 0.f;
    for (int m = 0; m < 128; ++m) s += ew2[kt * 128 + m] * nw1[(128 + m) * 128 + o];
    NW1t[o * 256 + 128 + kt] = f2bf(s);
  } else if (idx < 16384 + 128) {
    int o = idx - 16384;
    float s = 0.f;
    for (int m = 0; m < 128; ++m) s += eb2[m] * nw1[(128 + m) * 128 + o];
    c0[o] = s;
  }
}

// ================= CSR build =================
__global__ void hist_kernel(const int* __restrict__ rowI, int* __restrict__ deg, int nE) {
  int e = blockIdx.x * 256 + threadIdx.x;
  if (e < nE) atomicAdd(&deg[rowI[e]], 1);
}

__global__ void scan_local_kernel(const int* __restrict__ deg, int* __restrict__ cursor,
                                  int* __restrict__ bsums) {
  __shared__ int s[256];
  int i = threadIdx.x, gidx = blockIdx.x * 256 + i;
  int v = deg[gidx];
  s[i] = v; __syncthreads();
#pragma unroll
  for (int off = 1; off < 256; off <<= 1) {
    int t = (i >= off) ? s[i - off] : 0;
    __syncthreads();
    s[i] += t;
    __syncthreads();
  }
  cursor[gidx] = s[i] - v;
  if (i == 255) bsums[blockIdx.x] = s[255];
}

__global__ void scan_blocks_kernel(int* __restrict__ bsums, int nb) {
  __shared__ int s[256];
  int i = threadIdx.x;
  int v = (i < nb) ? bsums[i] : 0;
  s[i] = v; __syncthreads();
#pragma unroll
  for (int off = 1; off < 256; off <<= 1) {
    int t = (i >= off) ? s[i - off] : 0;
    __syncthreads();
    s[i] += t;
    __syncthreads();
  }
  if (i < nb) bsums[i] = s[i] - v;
}

// writes both cursor (mutated by scatter) and rowptr (kept for edge_agg)
__global__ void finalize_kernel(int* __restrict__ cursor, const int* __restrict__ bsums,
                                int* __restrict__ rowptr) {
  int i = blockIdx.x * 256 + threadIdx.x;
  int v = cursor[i] + bsums[i >> 8];
  cursor[i] = v;
  rowptr[i] = v;
}

// new path: colS only
__global__ void scatter2_kernel(const int* __restrict__ ei, int* __restrict__ cursor,
                                int* __restrict__ colS, int nE) {
  int e = blockIdx.x * 256 + threadIdx.x;
  if (e < nE) {
    int r = ei[e];
    int pos = atomicAdd(&cursor[r], 1);
    colS[pos] = ei[nE + e];
  }
}

// fallback path: rowS + colS
__global__ void scatter_kernel(const int* __restrict__ ei, int* __restrict__ cursor,
                               int* __restrict__ rowS, int* __restrict__ colS, int nE) {
  int e = blockIdx.x * 256 + threadIdx.x;
  if (e < nE) {
    int r = ei[e];
    int pos = atomicAdd(&cursor[r], 1);
    rowS[pos] = r;
    colS[pos] = ei[nE + e];
  }
}

// ================= g = h @ e_w1 (bf16 out) =================
__global__ __launch_bounds__(256) void g_kernel(
    const float* __restrict__ h, const short* __restrict__ W1t,
    unsigned short* __restrict__ gOut, int nN) {
  __shared__ __align__(16) char sW[32768];
  __shared__ __align__(16) char sX[16384];   // 64 rows x 256B; reused as bf16 out stage

  const int tid = threadIdx.x;
  const int lane = tid & 63, wv = tid >> 6;
  const int lr = lane & 15, grp = lane >> 4;
  const int nb = blockIdx.x * 64;

#pragma unroll
  for (int i = 0; i < 8; ++i) {
    int c = i * 256 + tid;
    int n = c >> 4, kB = (c & 15) * 16;
    *(int4*)(sW + swzB(n, kB, 256)) = ((const int4*)W1t)[c];
  }
  {
    int row = tid >> 2;
    int node = nb + row;
    int nd = (node < nN) ? node : 0;
#pragma unroll
    for (int it = 0; it < 8; ++it) {
      int c4 = (tid & 3) + it * 4;
      f32x4 v = *(const f32x4*)(h + (long)nd * 128 + c4 * 4);
      s16x4 p;
      p.x = f2bf(v.x); p.y = f2bf(v.y); p.z = f2bf(v.z); p.w = f2bf(v.w);
      *(s16x4*)(sX + swzB(row, c4 * 8, 256)) = p;
    }
  }
  __syncthreads();

  f32x4 acc[8];
#pragma unroll
  for (int j = 0; j < 8; ++j) acc[j] = (f32x4){0.f, 0.f, 0.f, 0.f};
#pragma unroll
  for (int kk = 0; kk < 4; ++kk) {
    int kB = (kk * 32 + grp * 8) * 2;
    bf16x8 a = *(const bf16x8*)(sX + swzB(wv * 16 + lr, kB, 256));
#pragma unroll
    for (int j = 0; j < 8; ++j) {
      bf16x8 b = *(const bf16x8*)(sW + swzB(j * 16 + lr, kB, 256));
      acc[j] = __builtin_amdgcn_mfma_f32_16x16x32_bf16(a, b, acc[j], 0, 0, 0);
    }
  }
  // bf16 results back into own sX rows (wave touches only its own 16 rows; in-wave order safe)
#pragma unroll
  for (int j = 0; j < 8; ++j) {
    int col = j * 16 + lr;
#pragma unroll
    for (int r = 0; r < 4; ++r) {
      int row = wv * 16 + grp * 4 + r;
      *(short*)(sX + row * 256 + ((col * 2) ^ ((row & 7) << 4))) = f2bf(acc[j][r]);
    }
  }
  __syncthreads();
  // vectorized store
#pragma unroll
  for (int i = 0; i < 4; ++i) {
    int c = i * 256 + tid;
    int row = c >> 4;
    int node = nb + row;
    if (node < nN) {
      int4 v = *(const int4*)(sX + row * 256 + (((c & 15) * 16) ^ ((row & 7) << 4)));
      ((int4*)gOut)[node * 16 + (c & 15)] = v;
    }
  }
}

// ================= edge aggregate: T[n] = sum relu(g[n]+b1 - g[col]) =================
__global__ __launch_bounds__(256) void edge_agg_kernel(
    const unsigned short* __restrict__ g, const int* __restrict__ rowptr,
    const int* __restrict__ deg, const int* __restrict__ colS,
    const float* __restrict__ b1, float* __restrict__ T, int nN) {
  const int tid = threadIdx.x;
  const int lane = tid & 63, wv = tid >> 6;
  const int lr = lane & 15, grp = lane >> 4;
  const int n = blockIdx.x * 4 + wv;
  if (n >= nN) return;

  const int rp = rowptr[n], dg = deg[n];
  u16x8 gu = *(const u16x8*)(g + n * 128 + lr * 8);
  float gnb[8];
#pragma unroll
  for (int j = 0; j < 8; ++j) gnb[j] = bf2f(gu[j]) + b1[lr * 8 + j];

  float acc[8] = {0.f, 0.f, 0.f, 0.f, 0.f, 0.f, 0.f, 0.f};
  for (int i = grp; i < dg; i += 4) {
    int c = colS[rp + i];
    u16x8 gc = *(const u16x8*)(g + (long)c * 128 + lr * 8);
#pragma unroll
    for (int j = 0; j < 8; ++j) {
      float d = gnb[j] - bf2f(gc[j]);
      acc[j] += (d > 0.f ? d : 0.f);
    }
  }
#pragma unroll
  for (int j = 0; j < 8; ++j) acc[j] += __shfl_xor(acc[j], 16);
#pragma unroll
  for (int j = 0; j < 8; ++j) acc[j] += __shfl_xor(acc[j], 32);

  if (grp == 0) {
    f32x4 o0 = {acc[0], acc[1], acc[2], acc[3]};
    f32x4 o1 = {acc[4], acc[5], acc[6], acc[7]};
    *(f32x4*)(T + (long)n * 128 + lr * 8) = o0;
    *(f32x4*)(T + (long)n * 128 + lr * 8 + 4) = o1;
  }
}

// ================= node kernel (new): out = relu(h@A + T@WB + deg*c0 + nb1)@NW2 + nb2 ====
__global__ __launch_bounds__(512) void node_kernel_new(
    const float* __restrict__ h, const float* T,    // T aliases out!
    const float* __restrict__ b1, const float* __restrict__ b2,
    const short* __restrict__ W1t, const short* __restrict__ W2t,
    const int* __restrict__ deg, const float* __restrict__ c0,
    float* out, int nN) {
  __shared__ __align__(16) char sZ[32768];
  __shared__ __align__(16) char sW1[65536];
  __shared__ __align__(16) char sW2[32768];
  __shared__ __align__(16) char sT[16384];

  const int tid = threadIdx.x;
  const int lane = tid & 63, wv = tid >> 6;
  const int lr = lane & 15, grp = lane >> 4;
  const int nb = blockIdx.x * 64;

#pragma unroll
  for (int i = 0; i < 8; ++i) {
    int c = i * 512 + tid;
    int n = c >> 5, kB = (c & 31) * 16;
    *(int4*)(sW1 + swzB(n, kB, 512)) = ((const int4*)W1t)[c];
  }
#pragma unroll
  for (int i = 0; i < 4; ++i) {
    int c = i * 512 + tid;
    int n = c >> 4, kB = (c & 15) * 16;
    *(int4*)(sW2 + swzB(n, kB, 256)) = ((const int4*)W2t)[c];
  }
  {
    int i = tid >> 3;
    int node = nb + i;
    bool ok = node < nN;
    int nd = ok ? node : 0;
#pragma unroll
    for (int it = 0; it < 8; ++it) {
      int c4 = (tid & 7) + it * 8;
      int col = c4 * 4;
      f32x4 v;
      if (col < 128) v = *(const f32x4*)(h + (long)nd * 128 + col);
      else           v = *(const f32x4*)(T + (long)nd * 128 + (col - 128));
      if (!ok) v = (f32x4){0.f, 0.f, 0.f, 0.f};
      s16x4 p;
      p.x = f2bf(v.x); p.y = f2bf(v.y); p.z = f2bf(v.z); p.w = f2bf(v.w);
      *(s16x4*)(sZ + swzB(i, col * 2, 512)) = p;
    }
  }
  __syncthreads();

  const int r0 = (wv >> 1) * 16;
  const int cb = (wv & 1) * 64;
  f32x4 acc[4];
#pragma unroll
  for (int j = 0; j < 4; ++j) acc[j] = (f32x4){0.f, 0.f, 0.f, 0.f};
#pragma unroll
  for (int kk = 0; kk < 8; ++kk) {
    int kB = (kk * 32 + grp * 8) * 2;
    bf16x8 a = *(const bf16x8*)(sZ + swzB(r0 + lr, kB, 512));
#pragma unroll
    for (int j = 0; j < 4; ++j) {
      bf16x8 b = *(const bf16x8*)(sW1 + swzB(cb + j * 16 + lr, kB, 512));
      acc[j] = __builtin_amdgcn_mfma_f32_16x16x32_bf16(a, b, acc[j], 0, 0, 0);
    }
  }
  float degs[4];
#pragma unroll
  for (int r = 0; r < 4; ++r) {
    int node = nb + r0 + grp * 4 + r;
    degs[r] = (float)deg[node];            // deg[N..NP) zeroed
  }
#pragma unroll
  for (int j = 0; j < 4; ++j) {
    int col = cb + j * 16 + lr;
    float bv = b1[col];
    float c0v = c0[col];
#pragma unroll
    for (int r = 0; r < 4; ++r) {
      int row = r0 + grp * 4 + r;
      float v = acc[j][r] + bv + degs[r] * c0v;
      v = v > 0.f ? v : 0.f;
      *(short*)(sT + swzB(row, col * 2, 256)) = f2bf(v);
    }
  }
  __syncthreads();

  f32x4 acc2[4];
#pragma unroll
  for (int j = 0; j < 4; ++j) acc2[j] = (f32x4){0.f, 0.f, 0.f, 0.f};
#pragma unroll
  for (int kk = 0; kk < 4; ++kk) {
    int kB = (kk * 32 + grp * 8) * 2;
    bf16x8 a = *(const bf16x8*)(sT + swzB(r0 + lr, kB, 256));
#pragma unroll
    for (int j = 0; j < 4; ++j) {
      bf16x8 b = *(const bf16x8*)(sW2 + swzB(cb + j * 16 + lr, kB, 256));
      acc2[j] = __builtin_amdgcn_mfma_f32_16x16x32_bf16(a, b, acc2[j], 0, 0, 0);
    }
  }
#pragma unroll
  for (int j = 0; j < 4; ++j) {
    int col = cb + j * 16 + lr;
    float bv = b2[col];
#pragma unroll
    for (int r = 0; r < 4; ++r) {
      int node = nb + r0 + grp * 4 + r;
      if (node < nN) out[(long)node * 128 + col] = acc2[j][r] + bv;
    }
  }
}

// ========================================================================
// ================= R3 fallback kernels (unchanged) ======================
// ========================================================================
__global__ void prep_kernel(const float* __restrict__ ew1, const float* __restrict__ ew2,
                            const float* __restrict__ nw1, const float* __restrict__ nw2,
                            short* __restrict__ wsS) {
  int idx = blockIdx.x * 256 + threadIdx.x;
  if (idx < 16384) {
    int n = idx >> 7, k = idx & 127;
    wsS[idx] = f2bf(ew1[k * 128 + n]);
  } else if (idx < 32768) {
    int o = idx - 16384; int n = o >> 7, k = o & 127;
    wsS[idx] = f2bf(ew2[k * 128 + n]);
  } else if (idx < 65536) {
    int o = idx - 32768; int n = o >> 8, k = o & 255;
    wsS[idx] = f2bf(nw1[k * 128 + n]);
  } else if (idx < 81920) {
    int o = idx - 65536; int n = o >> 7, k = o & 127;
    wsS[idx] = f2bf(nw2[k * 128 + n]);
  }
}

__global__ __launch_bounds__(512, 4) void edge_csr_kernel(
    const float* __restrict__ h, const int* __restrict__ rowS, const int* __restrict__ colS,
    const float* __restrict__ b1, const float* __restrict__ b2,
    const short* __restrict__ W1t, const short* __restrict__ W2t,
    float* __restrict__ agg, int nE) {
  __shared__ __align__(16) char sm[65536];
  __shared__ int rs[128];
  char* sW = sm;
  char* sT = sm + 32768;
  float* stg = (float*)sm;

  const int tid = threadIdx.x;
  const int lane = tid & 63, wv = tid >> 6;
  const int lr = lane & 15, grp = lane >> 4;
  const int eb = blockIdx.x * 128;

  if (tid < 128) rs[tid] = (eb + tid < nE) ? rowS[eb + tid] : -1;

#pragma unroll
  for (int i = 0; i < 4; ++i) {
    int c = i * 512 + tid;
    int n = c >> 4, kB = (c & 15) * 16;
    *(int4*)(sW + swzB(n, kB, 256)) = ((const int4*)W1t)[c];
  }
  bf16x8 afr[4];
  {
    int slot = eb + wv * 16 + lr;
    int r = 0, cc = 0;
    if (slot < nE) { r = rowS[slot]; cc = colS[slot]; }
    const float* hr = h + (long)r * 128;
    const float* hc = h + (long)cc * 128;
#pragma unroll
    for (int kk = 0; kk < 4; ++kk) {
      int k0 = kk * 32 + grp * 8;
      f32x4 a0 = *(const f32x4*)(hr + k0), a1 = *(const f32x4*)(hr + k0 + 4);
      f32x4 c0_ = *(const f32x4*)(hc + k0), c1 = *(const f32x4*)(hc + k0 + 4);
      union { bf16x8 v; short s[8]; } u;
      u.s[0] = f2bf(a0.x - c0_.x); u.s[1] = f2bf(a0.y - c0_.y);
      u.s[2] = f2bf(a0.z - c0_.z); u.s[3] = f2bf(a0.w - c0_.w);
      u.s[4] = f2bf(a1.x - c1.x); u.s[5] = f2bf(a1.y - c1.y);
      u.s[6] = f2bf(a1.z - c1.z); u.s[7] = f2bf(a1.w - c1.w);
      afr[kk] = u.v;
    }
  }
  __syncthreads();

  f32x4 acc[8];
#pragma unroll
  for (int j = 0; j < 8; ++j) acc[j] = (f32x4){0.f, 0.f, 0.f, 0.f};
#pragma unroll
  for (int kk = 0; kk < 4; ++kk) {
    int kB = (kk * 32 + grp * 8) * 2;
#pragma unroll
    for (int j = 0; j < 8; ++j) {
      bf16x8 b = *(const bf16x8*)(sW + swzB(j * 16 + lr, kB, 256));
      acc[j] = __builtin_amdgcn_mfma_f32_16x16x32_bf16(afr[kk], b, acc[j], 0, 0, 0);
    }
  }
#pragma unroll
  for (int j = 0; j < 8; ++j) {
    int col = j * 16 + lr;
    float bv = b1[col];
#pragma unroll
    for (int r = 0; r < 4; ++r) {
      int row = wv * 16 + grp * 4 + r;
      float v = acc[j][r] + bv;
      v = v > 0.f ? v : 0.f;
      *(short*)(sT + swzB(row, col * 2, 256)) = f2bf(v);
    }
  }
  __syncthreads();

#pragma unroll
  for (int i = 0; i < 4; ++i) {
    int c = i * 512 + tid;
    int n = c >> 4, kB = (c & 15) * 16;
    *(int4*)(sW + swzB(n, kB, 256)) = ((const int4*)W2t)[c];
  }
  __syncthreads();

  f32x4 acc2[8];
#pragma unroll
  for (int j = 0; j < 8; ++j) acc2[j] = (f32x4){0.f, 0.f, 0.f, 0.f};
#pragma unroll
  for (int kk = 0; kk < 4; ++kk) {
    int kB = (kk * 32 + grp * 8) * 2;
    bf16x8 a = *(const bf16x8*)(sT + swzB(wv * 16 + lr, kB, 256));
#pragma unroll
    for (int j = 0; j < 8; ++j) {
      bf16x8 b = *(const bf16x8*)(sW + swzB(j * 16 + lr, kB, 256));
      acc2[j] = __builtin_amdgcn_mfma_f32_16x16x32_bf16(a, b, acc2[j], 0, 0, 0);
    }
  }
  __syncthreads();

#pragma unroll
  for (int j = 0; j < 8; ++j) {
    int col = j * 16 + lr;
    float bv = b2[col];
#pragma unroll
    for (int r = 0; r < 4; ++r) {
      int row = wv * 16 + grp * 4 + r;
      *(float*)((char*)stg + row * 512 + ((col * 4) ^ ((row & 7) << 4))) = acc2[j][r] + bv;
    }
  }
  __syncthreads();

  {
    int c = tid & 127, q = tid >> 7;
    float run = 0.f;
    int cur = rs[q * 32];
    for (int i = 0; i < 32; ++i) {
      int row = q * 32 + i;
      int rr = rs[row];
      float v = *(const float*)((const char*)stg + row * 512 + ((c * 4) ^ ((row & 7) << 4)));
      if (rr != cur) {
        if (cur >= 0) atomicAdd(agg + (long)cur * 128 + c, run);
        run = 0.f; cur = rr;
      }
      run += v;
    }
    if (cur >= 0) atomicAdd(agg + (long)cur * 128 + c, run);
  }
}

__global__ __launch_bounds__(512) void node_kernel_old(
    const float* __restrict__ h, const float* agg,
    const float* __restrict__ b1, const float* __restrict__ b2,
    const short* __restrict__ W1t, const short* __restrict__ W2t,
    float* out, int nN) {
  __shared__ __align__(16) char sZ[32768];
  __shared__ __align__(16) char sW1[65536];
  __shared__ __align__(16) char sW2[32768];
  __shared__ __align__(16) char sT[16384];

  const int tid = threadIdx.x;
  const int lane = tid & 63, wv = tid >> 6;
  const int lr = lane & 15, grp = lane >> 4;
  const int nb = blockIdx.x * 64;

#pragma unroll
  for (int i = 0; i < 8; ++i) {
    int c = i * 512 + tid;
    int n = c >> 5, kB = (c & 31) * 16;
    *(int4*)(sW1 + swzB(n, kB, 512)) = ((const int4*)W1t)[c];
  }
#pragma unroll
  for (int i = 0; i < 4; ++i) {
    int c = i * 512 + tid;
    int n = c >> 4, kB = (c & 15) * 16;
    *(int4*)(sW2 + swzB(n, kB, 256)) = ((const int4*)W2t)[c];
  }
  {
    int i = tid >> 3;
    int node = nb + i;
    bool ok = node < nN;
    int nd = ok ? node : 0;
#pragma unroll
    for (int it = 0; it < 8; ++it) {
      int c4 = (tid & 7) + it * 8;
      int col = c4 * 4;
      f32x4 v;
      if (col < 128) v = *(const f32x4*)(h + (long)nd * 128 + col);
      else           v = *(const f32x4*)(agg + (long)nd * 128 + (col - 128));
      if (!ok) v = (f32x4){0.f, 0.f, 0.f, 0.f};
      s16x4 p;
      p.x = f2bf(v.x); p.y = f2bf(v.y); p.z = f2bf(v.z); p.w = f2bf(v.w);
      *(s16x4*)(sZ + swzB(i, col * 2, 512)) = p;
    }
  }
  __syncthreads();

  const int r0 = (wv >> 1) * 16;
  const int cb = (wv & 1) * 64;
  f32x4 acc[4];
#pragma unroll
  for (int j = 0; j < 4; ++j) acc[j] = (f32x4){0.f, 0.f, 0.f, 0.f};
#pragma unroll
  for (int kk = 0; kk < 8; ++kk) {
    int kB = (kk * 32 + grp * 8) * 2;
    bf16x8 a = *(const bf16x8*)(sZ + swzB(r0 + lr, kB, 512));
#pragma unroll
    for (int j = 0; j < 4; ++j) {
      bf16x8 b = *(const bf16x8*)(sW1 + swzB(cb + j * 16 + lr, kB, 512));
      acc[j] = __builtin_amdgcn_mfma_f32_16x16x32_bf16(a, b, acc[j], 0, 0, 0);
    }
  }
#pragma unroll
  for (int j = 0; j < 4; ++j) {
    int col = cb + j * 16 + lr;
    float bv = b1[col];
#pragma unroll
    for (int r = 0; r < 4; ++r) {
      int row = r0 + grp * 4 + r;
      float v = acc[j][r] + bv;
      v = v > 0.f ? v : 0.f;
      *(short*)(sT + swzB(row, col * 2, 256)) = f2bf(v);
    }
  }
  __syncthreads();

  f32x4 acc2[4];
#pragma unroll
  for (int j = 0; j < 4; ++j) acc2[j] = (f32x4){0.f, 0.f, 0.f, 0.f};
#pragma unroll
  for (int kk = 0; kk < 4; ++kk) {
    int kB = (kk * 32 + grp * 8) * 2;
    bf16x8 a = *(const bf16x8*)(sT + swzB(r0 + lr, kB, 256));
#pragma unroll
    for (int j = 0; j < 4; ++j) {
      bf16x8 b = *(const bf16x8*)(sW2 + swzB(cb + j * 16 + lr, kB, 256));
      acc2[j] = __builtin_amdgcn_mfma_f32_16x16x32_bf16(a, b, acc2[j], 0, 0, 0);
    }
  }
#pragma unroll
  for (int j = 0; j < 4; ++j) {
    int col = cb + j * 16 + lr;
    float bv = b2[col];
#pragma unroll
    for (int r = 0; r < 4; ++r) {
      int node = nb + r0 + grp * 4 + r;
      if (node < nN) out[(long)node * 128 + col] = acc2[j][r] + bv;
    }
  }
}

// ========================================================================
extern "C" void kernel_launch(void* const* d_in, const int* in_sizes, int n_in,
                              void* d_out, int out_size, void* d_ws, size_t ws_size,
                              hipStream_t stream) {
  const float* h   = (const float*)d_in[0];
  const int*   ei  = (const int*)d_in[1];
  const float* ew1 = (const float*)d_in[2];
  const float* eb1 = (const float*)d_in[3];
  const float* ew2 = (const float*)d_in[4];
  const float* eb2 = (const float*)d_in[5];
  const float* nw1 = (const float*)d_in[6];
  const float* nb1 = (const float*)d_in[7];
  const float* nw2 = (const float*)d_in[8];
  const float* nb2 = (const float*)d_in[9];
  float* out = (float*)d_out;

  const int E = in_sizes[1] / 2;            // 600000
  const int N = in_sizes[0] / 128;          // 50000
  const int NP = ((N + 255) / 256) * 256;   // 50176
  const int NB = NP / 256;                  // 196

  // ---- new-path ws layout ----
  char* base = (char*)d_ws;
  short* W1t   = (short*)base;                     // 16384
  short* NW1t  = W1t + 16384;                      // 32768
  short* NW2t  = NW1t + 32768;                     // 16384
  float* c0    = (float*)(NW2t + 16384);           // 128
  int*   deg   = (int*)(c0 + 128);                 // NP
  int*   cursor= deg + NP;                         // NP
  int*   rowptr= cursor + NP;                      // NP
  int*   bsums = rowptr + NP;                      // 256
  int*   colS  = bsums + 256;                      // E
  size_t goff  = (((size_t)((char*)(colS + E) - base)) + 15) & ~(size_t)15;
  unsigned short* g = (unsigned short*)(base + goff);   // NP*128 bf16
  size_t needed_new = goff + (size_t)NP * 256;

  if (ws_size >= needed_new) {
    hipMemsetAsync(deg, 0, (size_t)NP * sizeof(int), stream);
    prep_new<<<192, 256, 0, stream>>>(ew1, nw1, nw2, W1t, NW1t, NW2t);
    wb_kernel<<<65, 256, 0, stream>>>(ew2, eb2, nw1, NW1t, c0);
    hist_kernel<<<(E + 255) / 256, 256, 0, stream>>>(ei, deg, E);
    g_kernel<<<(N + 63) / 64, 256, 0, stream>>>(h, W1t, g, N);
    scan_local_kernel<<<NB, 256, 0, stream>>>(deg, cursor, bsums);
    scan_blocks_kernel<<<1, 256, 0, stream>>>(bsums, NB);
    finalize_kernel<<<NB, 256, 0, stream>>>(cursor, bsums, rowptr);
    scatter2_kernel<<<(E + 255) / 256, 256, 0, stream>>>(ei, cursor, colS, E);
    edge_agg_kernel<<<(N + 3) / 4, 256, 0, stream>>>(g, rowptr, deg, colS, eb1, out, N);
    node_kernel_new<<<(N + 63) / 64, 512, 0, stream>>>(h, out, nb1, nb2, NW1t, NW2t,
                                                       deg, c0, out, N);
    return;
  }

  // ---- R3 fallback ----
  short* wsS   = (short*)d_ws;
  short* fW1t  = wsS;
  short* fW2t  = wsS + 16384;
  short* fNW1t = wsS + 32768;
  short* fNW2t = wsS + 65536;
  int* fdeg    = (int*)(wsS + 81920);
  int* fcursor = fdeg + NP;
  int* fbsums  = fcursor + NP;
  int* frowS   = fbsums + 256;
  int* fcolS   = frowS + ((E + 63) & ~63);
  size_t needed_old = (size_t)((char*)(fcolS + E) - (char*)d_ws);

  hipMemsetAsync(d_out, 0, (size_t)out_size * sizeof(float), stream);
  prep_kernel<<<320, 256, 0, stream>>>(ew1, ew2, nw1, nw2, wsS);

  if (ws_size >= needed_old) {
    hipMemsetAsync(fdeg, 0, (size_t)(2 * NP + 256) * sizeof(int), stream);
    hist_kernel<<<(E + 255) / 256, 256, 0, stream>>>(ei, fdeg, E);
    scan_local_kernel<<<NB, 256, 0, stream>>>(fdeg, fcursor, fbsums);
    scan_blocks_kernel<<<1, 256, 0, stream>>>(fbsums, NB);
    finalize_kernel<<<NB, 256, 0, stream>>>(fcursor, fbsums, fcursor);
    scatter_kernel<<<(E + 255) / 256, 256, 0, stream>>>(ei, fcursor, frowS, fcolS, E);
    edge_csr_kernel<<<(E + 127) / 128, 512, 0, stream>>>(h, frowS, fcolS, eb1, eb2,
                                                         fW1t, fW2t, out, E);
  }
  node_kernel_old<<<(N + 63) / 64, 512, 0, stream>>>(h, out, nb1, nb2, fNW1t, fNW2t, out, N);
}

// Round 5
// 145.861 us; speedup vs baseline: 2.7747x; 1.0730x over previous
//
#include <hip/hip_runtime.h>
#include <hip/hip_bf16.h>

// GraphConv layer, R5.
//   g = h@e_w1 (bf16/node).  T[n] = sum_edges relu(g[n]+b1 - g[col])  (t-space aggregate).
//   out = relu(h@A + T@(e_w2@B) + deg*(e_b2@B) + n_b1)@n_w2 + n_b2   (folded node MLP).
// R5 changes: prep_all fuses weight prep + WB fold + deg zeroing (no memsets, 9 launches);
//   T stored bf16 (halves round-trip, precision-identical); edge_agg prefetches colS;
//   g_kernel builds A-fragments directly from global.

typedef __attribute__((ext_vector_type(4))) float f32x4;
typedef __attribute__((ext_vector_type(8))) __bf16 bf16x8;
typedef __attribute__((ext_vector_type(4))) short s16x4;
typedef __attribute__((ext_vector_type(8))) unsigned short u16x8;

__device__ __forceinline__ short f2bf(float f) {
  unsigned x = __float_as_uint(f);
  x = (x + 0x7fffu + ((x >> 16) & 1u)) >> 16;
  return (short)x;
}
__device__ __forceinline__ float bf2f(unsigned short u) {
  return __uint_as_float(((unsigned)u) << 16);
}
// XOR swizzle on byte bits 4..6 within a row (G4 / m214 r268)
__device__ __forceinline__ int swzB(int row, int colByte, int strideB) {
  return row * strideB + (colByte ^ ((row & 7) << 4));
}

// ================= prep_all: all weight prep + WB fold + zero deg (one kernel) ======
// ranges: [0,16K) W1t | [16K,32K) NW1t-h | [32K,48K) NW2t | [48K,64K) WB | c0 | zero deg
__global__ void prep_all(const float* __restrict__ ew1, const float* __restrict__ ew2,
                         const float* __restrict__ eb2, const float* __restrict__ nw1,
                         const float* __restrict__ nw2, short* __restrict__ W1t,
                         short* __restrict__ NW1t, short* __restrict__ NW2t,
                         float* __restrict__ c0, int* __restrict__ deg, int degInt4) {
  int idx = blockIdx.x * 256 + threadIdx.x;
  if (idx < 16384) {                        // W1t [128o][128k] <- e_w1
    int n = idx >> 7, k = idx & 127;
    W1t[idx] = f2bf(ew1[k * 128 + n]);
  } else if (idx < 32768) {                 // NW1t [128o][256k], k<128 <- n_w1[:128]
    int o = idx - 16384; int n = o >> 7, k = o & 127;
    NW1t[n * 256 + k] = f2bf(nw1[k * 128 + n]);
  } else if (idx < 49152) {                 // NW2t [128o][128k] <- n_w2
    int o = idx - 32768; int n = o >> 7, k = o & 127;
    NW2t[o] = f2bf(nw2[k * 128 + n]);
  } else if (idx < 65536) {                 // WB[kt][o] = e_w2[kt,:]@n_w1[128:,o] -> k=128+kt
    int o = idx - 49152; int ocol = o & 127, kt = o >> 7;
    float s = 0.f;
    for (int m = 0; m < 128; ++m) s += ew2[kt * 128 + m] * nw1[(128 + m) * 128 + ocol];
    NW1t[ocol * 256 + 128 + kt] = f2bf(s);
  } else if (idx < 65664) {                 // c0[o] = e_b2@n_w1[128:,o]
    int o = idx - 65536;
    float s = 0.f;
    for (int m = 0; m < 128; ++m) s += eb2[m] * nw1[(128 + m) * 128 + o];
    c0[o] = s;
  } else if (idx < 65664 + degInt4) {       // zero deg (int4 stores)
    ((int4*)deg)[idx - 65664] = (int4){0, 0, 0, 0};
  }
}

// ================= CSR build =================
__global__ void hist_kernel(const int* __restrict__ rowI, int* __restrict__ deg, int nE) {
  int e = blockIdx.x * 256 + threadIdx.x;
  if (e < nE) atomicAdd(&deg[rowI[e]], 1);
}

__global__ void scan_local_kernel(const int* __restrict__ deg, int* __restrict__ cursor,
                                  int* __restrict__ bsums) {
  __shared__ int s[256];
  int i = threadIdx.x, gidx = blockIdx.x * 256 + i;
  int v = deg[gidx];
  s[i] = v; __syncthreads();
#pragma unroll
  for (int off = 1; off < 256; off <<= 1) {
    int t = (i >= off) ? s[i - off] : 0;
    __syncthreads();
    s[i] += t;
    __syncthreads();
  }
  cursor[gidx] = s[i] - v;
  if (i == 255) bsums[blockIdx.x] = s[255];
}

__global__ void scan_blocks_kernel(int* __restrict__ bsums, int nb) {
  __shared__ int s[256];
  int i = threadIdx.x;
  int v = (i < nb) ? bsums[i] : 0;
  s[i] = v; __syncthreads();
#pragma unroll
  for (int off = 1; off < 256; off <<= 1) {
    int t = (i >= off) ? s[i - off] : 0;
    __syncthreads();
    s[i] += t;
    __syncthreads();
  }
  if (i < nb) bsums[i] = s[i] - v;
}

__global__ void finalize_kernel(int* __restrict__ cursor, const int* __restrict__ bsums,
                                int* __restrict__ rowptr) {
  int i = blockIdx.x * 256 + threadIdx.x;
  int v = cursor[i] + bsums[i >> 8];
  cursor[i] = v;
  rowptr[i] = v;
}

__global__ void scatter2_kernel(const int* __restrict__ ei, int* __restrict__ cursor,
                                int* __restrict__ colS, int nE) {
  int e = blockIdx.x * 256 + threadIdx.x;
  if (e < nE) {
    int r = ei[e];
    int pos = atomicAdd(&cursor[r], 1);
    colS[pos] = ei[nE + e];
  }
}

// ================= g = h @ e_w1 (bf16 out), A direct from global =================
__global__ __launch_bounds__(256) void g_kernel(
    const float* __restrict__ h, const short* __restrict__ W1t,
    unsigned short* __restrict__ gOut, int nN) {
  __shared__ __align__(16) char sW[32768];
  __shared__ __align__(16) char sO[16384];   // bf16 out stage, 64 rows x 256B

  const int tid = threadIdx.x;
  const int lane = tid & 63, wv = tid >> 6;
  const int lr = lane & 15, grp = lane >> 4;
  const int nb = blockIdx.x * 64;

#pragma unroll
  for (int i = 0; i < 8; ++i) {
    int c = i * 256 + tid;
    int n = c >> 4, kB = (c & 15) * 16;
    *(int4*)(sW + swzB(n, kB, 256)) = ((const int4*)W1t)[c];
  }
  // A-fragments direct from global h
  bf16x8 afr[4];
  {
    int row = nb + wv * 16 + lr;
    int nd = (row < nN) ? row : 0;
    const float* hr = h + (long)nd * 128;
#pragma unroll
    for (int kk = 0; kk < 4; ++kk) {
      int k0 = kk * 32 + grp * 8;
      f32x4 a0 = *(const f32x4*)(hr + k0), a1 = *(const f32x4*)(hr + k0 + 4);
      union { bf16x8 v; short s[8]; } u;
      u.s[0] = f2bf(a0.x); u.s[1] = f2bf(a0.y); u.s[2] = f2bf(a0.z); u.s[3] = f2bf(a0.w);
      u.s[4] = f2bf(a1.x); u.s[5] = f2bf(a1.y); u.s[6] = f2bf(a1.z); u.s[7] = f2bf(a1.w);
      afr[kk] = u.v;
    }
  }
  __syncthreads();

  f32x4 acc[8];
#pragma unroll
  for (int j = 0; j < 8; ++j) acc[j] = (f32x4){0.f, 0.f, 0.f, 0.f};
#pragma unroll
  for (int kk = 0; kk < 4; ++kk) {
    int kB = (kk * 32 + grp * 8) * 2;
#pragma unroll
    for (int j = 0; j < 8; ++j) {
      bf16x8 b = *(const bf16x8*)(sW + swzB(j * 16 + lr, kB, 256));
      acc[j] = __builtin_amdgcn_mfma_f32_16x16x32_bf16(afr[kk], b, acc[j], 0, 0, 0);
    }
  }
#pragma unroll
  for (int j = 0; j < 8; ++j) {
    int col = j * 16 + lr;
#pragma unroll
    for (int r = 0; r < 4; ++r) {
      int row = wv * 16 + grp * 4 + r;
      *(short*)(sO + row * 256 + ((col * 2) ^ ((row & 7) << 4))) = f2bf(acc[j][r]);
    }
  }
  __syncthreads();
#pragma unroll
  for (int i = 0; i < 4; ++i) {
    int c = i * 256 + tid;
    int row = c >> 4;
    int node = nb + row;
    if (node < nN) {
      int4 v = *(const int4*)(sO + row * 256 + (((c & 15) * 16) ^ ((row & 7) << 4)));
      ((int4*)gOut)[node * 16 + (c & 15)] = v;
    }
  }
}

// ================= edge aggregate: Tb[n] = bf16( sum relu(g[n]+b1 - g[col]) ) ==========
__global__ __launch_bounds__(256) void edge_agg_kernel(
    const unsigned short* __restrict__ g, const int* __restrict__ rowptr,
    const int* __restrict__ deg, const int* __restrict__ colS,
    const float* __restrict__ b1, unsigned short* __restrict__ Tb, int nN) {
  const int tid = threadIdx.x;
  const int lane = tid & 63, wv = tid >> 6;
  const int lr = lane & 15, grp = lane >> 4;
  const int n = blockIdx.x * 4 + wv;
  if (n >= nN) return;

  const int rp = rowptr[n], dg = deg[n];
  u16x8 gu = *(const u16x8*)(g + (long)n * 128 + lr * 8);
  float gnb[8];
#pragma unroll
  for (int j = 0; j < 8; ++j) gnb[j] = bf2f(gu[j]) + b1[lr * 8 + j];

  float acc[8] = {0.f, 0.f, 0.f, 0.f, 0.f, 0.f, 0.f, 0.f};
  int i = grp;
  if (i < dg) {
    int c = colS[rp + i];
    while (true) {
      u16x8 gc = *(const u16x8*)(g + (long)c * 128 + lr * 8);
      i += 4;
      bool more = (i < dg);
      int cn = 0;
      if (more) cn = colS[rp + i];   // prefetch next col index under the gather+compute
#pragma unroll
      for (int j = 0; j < 8; ++j) {
        float d = gnb[j] - bf2f(gc[j]);
        acc[j] += (d > 0.f ? d : 0.f);
      }
      if (!more) break;
      c = cn;
    }
  }
#pragma unroll
  for (int j = 0; j < 8; ++j) acc[j] += __shfl_xor(acc[j], 16);
#pragma unroll
  for (int j = 0; j < 8; ++j) acc[j] += __shfl_xor(acc[j], 32);

  if (grp == 0) {
    union { u16x8 v; unsigned short s[8]; } o;
#pragma unroll
    for (int j = 0; j < 8; ++j) o.s[j] = (unsigned short)f2bf(acc[j]);
    *(u16x8*)(Tb + (long)n * 128 + lr * 8) = o.v;
  }
}

// ============ node kernel: out = relu(h@A + Tb@WB + deg*c0 + nb1)@NW2 + nb2 ============
__global__ __launch_bounds__(512) void node_kernel_new(
    const float* __restrict__ h, const unsigned short* __restrict__ Tb,
    const float* __restrict__ b1, const float* __restrict__ b2,
    const short* __restrict__ W1t, const short* __restrict__ W2t,
    const int* __restrict__ deg, const float* __restrict__ c0,
    float* __restrict__ out, int nN) {
  __shared__ __align__(16) char sZ[32768];    // z tile [64][256] bf16
  __shared__ __align__(16) char sW1[65536];   // NW1t [128o][256k]
  __shared__ __align__(16) char sW2[32768];
  __shared__ __align__(16) char sT[16384];

  const int tid = threadIdx.x;
  const int lane = tid & 63, wv = tid >> 6;
  const int lr = lane & 15, grp = lane >> 4;
  const int nb = blockIdx.x * 64;

#pragma unroll
  for (int i = 0; i < 8; ++i) {
    int c = i * 512 + tid;
    int n = c >> 5, kB = (c & 31) * 16;
    *(int4*)(sW1 + swzB(n, kB, 512)) = ((const int4*)W1t)[c];
  }
#pragma unroll
  for (int i = 0; i < 4; ++i) {
    int c = i * 512 + tid;
    int n = c >> 4, kB = (c & 15) * 16;
    *(int4*)(sW2 + swzB(n, kB, 256)) = ((const int4*)W2t)[c];
  }
  // stage z = [bf16(h) | Tb] (8 threads per row)
  {
    int i = tid >> 3;
    int node = nb + i;
    bool ok = node < nN;
    int nd = ok ? node : 0;
#pragma unroll
    for (int it = 0; it < 4; ++it) {
      int c4 = (tid & 7) + it * 8;            // f32x4 index 0..31 (cols 0..127)
      f32x4 v = ok ? *(const f32x4*)(h + (long)nd * 128 + c4 * 4)
                   : (f32x4){0.f, 0.f, 0.f, 0.f};
      s16x4 p;
      p.x = f2bf(v.x); p.y = f2bf(v.y); p.z = f2bf(v.z); p.w = f2bf(v.w);
      *(s16x4*)(sZ + swzB(i, c4 * 8, 512)) = p;
    }
#pragma unroll
    for (int it = 0; it < 2; ++it) {
      int cc = (tid & 7) + it * 8;            // 16B chunk 0..15 of Tb row (cols 128..255)
      int4 v = ok ? ((const int4*)(Tb + (long)nd * 128))[cc] : (int4){0, 0, 0, 0};
      *(int4*)(sZ + swzB(i, 256 + cc * 16, 512)) = v;
    }
  }
  __syncthreads();

  const int r0 = (wv >> 1) * 16;
  const int cb = (wv & 1) * 64;
  f32x4 acc[4];
#pragma unroll
  for (int j = 0; j < 4; ++j) acc[j] = (f32x4){0.f, 0.f, 0.f, 0.f};
#pragma unroll
  for (int kk = 0; kk < 8; ++kk) {
    int kB = (kk * 32 + grp * 8) * 2;
    bf16x8 a = *(const bf16x8*)(sZ + swzB(r0 + lr, kB, 512));
#pragma unroll
    for (int j = 0; j < 4; ++j) {
      bf16x8 b = *(const bf16x8*)(sW1 + swzB(cb + j * 16 + lr, kB, 512));
      acc[j] = __builtin_amdgcn_mfma_f32_16x16x32_bf16(a, b, acc[j], 0, 0, 0);
    }
  }
  float degs[4];
#pragma unroll
  for (int r = 0; r < 4; ++r) {
    int node = nb + r0 + grp * 4 + r;
    degs[r] = (float)deg[node];               // deg zeroed through NP
  }
#pragma unroll
  for (int j = 0; j < 4; ++j) {
    int col = cb + j * 16 + lr;
    float bv = b1[col];
    float c0v = c0[col];
#pragma unroll
    for (int r = 0; r < 4; ++r) {
      int row = r0 + grp * 4 + r;
      float v = acc[j][r] + bv + degs[r] * c0v;
      v = v > 0.f ? v : 0.f;
      *(short*)(sT + swzB(row, col * 2, 256)) = f2bf(v);
    }
  }
  __syncthreads();

  f32x4 acc2[4];
#pragma unroll
  for (int j = 0; j < 4; ++j) acc2[j] = (f32x4){0.f, 0.f, 0.f, 0.f};
#pragma unroll
  for (int kk = 0; kk < 4; ++kk) {
    int kB = (kk * 32 + grp * 8) * 2;
    bf16x8 a = *(const bf16x8*)(sT + swzB(r0 + lr, kB, 256));
#pragma unroll
    for (int j = 0; j < 4; ++j) {
      bf16x8 b = *(const bf16x8*)(sW2 + swzB(cb + j * 16 + lr, kB, 256));
      acc2[j] = __builtin_amdgcn_mfma_f32_16x16x32_bf16(a, b, acc2[j], 0, 0, 0);
    }
  }
#pragma unroll
  for (int j = 0; j < 4; ++j) {
    int col = cb + j * 16 + lr;
    float bv = b2[col];
#pragma unroll
    for (int r = 0; r < 4; ++r) {
      int node = nb + r0 + grp * 4 + r;
      if (node < nN) out[(long)node * 128 + col] = acc2[j][r] + bv;
    }
  }
}

// ========================================================================
// ================= minimal fallback (per-edge atomics, 160KB ws) ========
// ========================================================================
__global__ void prep_kernel_fb(const float* __restrict__ ew1, const float* __restrict__ ew2,
                               const float* __restrict__ nw1, const float* __restrict__ nw2,
                               short* __restrict__ wsS) {
  int idx = blockIdx.x * 256 + threadIdx.x;
  if (idx < 16384) {
    int n = idx >> 7, k = idx & 127;
    wsS[idx] = f2bf(ew1[k * 128 + n]);
  } else if (idx < 32768) {
    int o = idx - 16384; int n = o >> 7, k = o & 127;
    wsS[idx] = f2bf(ew2[k * 128 + n]);
  } else if (idx < 65536) {
    int o = idx - 32768; int n = o >> 8, k = o & 255;
    wsS[idx] = f2bf(nw1[k * 128 + n]);
  } else if (idx < 81920) {
    int o = idx - 65536; int n = o >> 7, k = o & 127;
    wsS[idx] = f2bf(nw2[k * 128 + n]);
  }
}

__global__ __launch_bounds__(512) void edge_kernel_fb(
    const float* __restrict__ h, const int* __restrict__ ei,
    const float* __restrict__ b1, const float* __restrict__ b2,
    const short* __restrict__ W1t, const short* __restrict__ W2t,
    float* __restrict__ agg, int nE) {
  __shared__ __align__(16) char sW1[32768];
  __shared__ __align__(16) char sW2[32768];
  __shared__ __align__(16) char sT[32768];

  const int tid = threadIdx.x;
  const int lane = tid & 63, wv = tid >> 6;
  const int lr = lane & 15, grp = lane >> 4;
  const int eb = blockIdx.x * 128;
  const int* rowI = ei;
  const int* colI = ei + nE;

#pragma unroll
  for (int i = 0; i < 4; ++i) {
    int c = i * 512 + tid;
    int n = c >> 4, kB = (c & 15) * 16;
    *(int4*)(sW1 + swzB(n, kB, 256)) = ((const int4*)W1t)[c];
    *(int4*)(sW2 + swzB(n, kB, 256)) = ((const int4*)W2t)[c];
  }
  bf16x8 afr[4];
  {
    int slot = eb + wv * 16 + lr;
    int r = 0, cc = 0;
    if (slot < nE) { r = rowI[slot]; cc = colI[slot]; }
    const float* hr = h + (long)r * 128;
    const float* hc = h + (long)cc * 128;
#pragma unroll
    for (int kk = 0; kk < 4; ++kk) {
      int k0 = kk * 32 + grp * 8;
      f32x4 a0 = *(const f32x4*)(hr + k0), a1 = *(const f32x4*)(hr + k0 + 4);
      f32x4 c0_ = *(const f32x4*)(hc + k0), c1 = *(const f32x4*)(hc + k0 + 4);
      union { bf16x8 v; short s[8]; } u;
      u.s[0] = f2bf(a0.x - c0_.x); u.s[1] = f2bf(a0.y - c0_.y);
      u.s[2] = f2bf(a0.z - c0_.z); u.s[3] = f2bf(a0.w - c0_.w);
      u.s[4] = f2bf(a1.x - c1.x); u.s[5] = f2bf(a1.y - c1.y);
      u.s[6] = f2bf(a1.z - c1.z); u.s[7] = f2bf(a1.w - c1.w);
      afr[kk] = u.v;
    }
  }
  __syncthreads();

  f32x4 acc[8];
#pragma unroll
  for (int j = 0; j < 8; ++j) acc[j] = (f32x4){0.f, 0.f, 0.f, 0.f};
#pragma unroll
  for (int kk = 0; kk < 4; ++kk) {
    int kB = (kk * 32 + grp * 8) * 2;
#pragma unroll
    for (int j = 0; j < 8; ++j) {
      bf16x8 b = *(const bf16x8*)(sW1 + swzB(j * 16 + lr, kB, 256));
      acc[j] = __builtin_amdgcn_mfma_f32_16x16x32_bf16(afr[kk], b, acc[j], 0, 0, 0);
    }
  }
#pragma unroll
  for (int j = 0; j < 8; ++j) {
    int col = j * 16 + lr;
    float bv = b1[col];
#pragma unroll
    for (int r = 0; r < 4; ++r) {
      int row = wv * 16 + grp * 4 + r;
      float v = acc[j][r] + bv;
      v = v > 0.f ? v : 0.f;
      *(short*)(sT + swzB(row, col * 2, 256)) = f2bf(v);
    }
  }
  __syncthreads();

  f32x4 acc2[8];
#pragma unroll
  for (int j = 0; j < 8; ++j) acc2[j] = (f32x4){0.f, 0.f, 0.f, 0.f};
#pragma unroll
  for (int kk = 0; kk < 4; ++kk) {
    int kB = (kk * 32 + grp * 8) * 2;
    bf16x8 a = *(const bf16x8*)(sT + swzB(wv * 16 + lr, kB, 256));
#pragma unroll
    for (int j = 0; j < 8; ++j) {
      bf16x8 b = *(const bf16x8*)(sW2 + swzB(j * 16 + lr, kB, 256));
      acc2[j] = __builtin_amdgcn_mfma_f32_16x16x32_bf16(a, b, acc2[j], 0, 0, 0);
    }
  }
  int nd[4]; bool okr[4];
#pragma unroll
  for (int r = 0; r < 4; ++r) {
    int e = eb + wv * 16 + grp * 4 + r;
    okr[r] = e < nE;
    nd[r] = okr[r] ? rowI[e] : 0;
  }
#pragma unroll
  for (int j = 0; j < 8; ++j) {
    int col = j * 16 + lr;
    float bv = b2[col];
#pragma unroll
    for (int r = 0; r < 4; ++r) {
      if (okr[r]) atomicAdd(agg + (long)nd[r] * 128 + col, acc2[j][r] + bv);
    }
  }
}

__global__ __launch_bounds__(512) void node_kernel_fb(
    const float* __restrict__ h, const float* agg,
    const float* __restrict__ b1, const float* __restrict__ b2,
    const short* __restrict__ W1t, const short* __restrict__ W2t,
    float* out, int nN) {
  __shared__ __align__(16) char sZ[32768];
  __shared__ __align__(16) char sW1[65536];
  __shared__ __align__(16) char sW2[32768];
  __shared__ __align__(16) char sT[16384];

  const int tid = threadIdx.x;
  const int lane = tid & 63, wv = tid >> 6;
  const int lr = lane & 15, grp = lane >> 4;
  const int nb = blockIdx.x * 64;

#pragma unroll
  for (int i = 0; i < 8; ++i) {
    int c = i * 512 + tid;
    int n = c >> 5, kB = (c & 31) * 16;
    *(int4*)(sW1 + swzB(n, kB, 512)) = ((const int4*)W1t)[c];
  }
#pragma unroll
  for (int i = 0; i < 4; ++i) {
    int c = i * 512 + tid;
    int n = c >> 4, kB = (c & 15) * 16;
    *(int4*)(sW2 + swzB(n, kB, 256)) = ((const int4*)W2t)[c];
  }
  {
    int i = tid >> 3;
    int node = nb + i;
    bool ok = node < nN;
    int nd = ok ? node : 0;
#pragma unroll
    for (int it = 0; it < 8; ++it) {
      int c4 = (tid & 7) + it * 8;
      int col = c4 * 4;
      f32x4 v;
      if (col < 128) v = *(const f32x4*)(h + (long)nd * 128 + col);
      else           v = *(const f32x4*)(agg + (long)nd * 128 + (col - 128));
      if (!ok) v = (f32x4){0.f, 0.f, 0.f, 0.f};
      s16x4 p;
      p.x = f2bf(v.x); p.y = f2bf(v.y); p.z = f2bf(v.z); p.w = f2bf(v.w);
      *(s16x4*)(sZ + swzB(i, col * 2, 512)) = p;
    }
  }
  __syncthreads();

  const int r0 = (wv >> 1) * 16;
  const int cb = (wv & 1) * 64;
  f32x4 acc[4];
#pragma unroll
  for (int j = 0; j < 4; ++j) acc[j] = (f32x4){0.f, 0.f, 0.f, 0.f};
#pragma unroll
  for (int kk = 0; kk < 8; ++kk) {
    int kB = (kk * 32 + grp * 8) * 2;
    bf16x8 a = *(const bf16x8*)(sZ + swzB(r0 + lr, kB, 512));
#pragma unroll
    for (int j = 0; j < 4; ++j) {
      bf16x8 b = *(const bf16x8*)(sW1 + swzB(cb + j * 16 + lr, kB, 512));
      acc[j] = __builtin_amdgcn_mfma_f32_16x16x32_bf16(a, b, acc[j], 0, 0, 0);
    }
  }
#pragma unroll
  for (int j = 0; j < 4; ++j) {
    int col = cb + j * 16 + lr;
    float bv = b1[col];
#pragma unroll
    for (int r = 0; r < 4; ++r) {
      int row = r0 + grp * 4 + r;
      float v = acc[j][r] + bv;
      v = v > 0.f ? v : 0.f;
      *(short*)(sT + swzB(row, col * 2, 256)) = f2bf(v);
    }
  }
  __syncthreads();

  f32x4 acc2[4];
#pragma unroll
  for (int j = 0; j < 4; ++j) acc2[j] = (f32x4){0.f, 0.f, 0.f, 0.f};
#pragma unroll
  for (int kk = 0; kk < 4; ++kk) {
    int kB = (kk * 32 + grp * 8) * 2;
    bf16x8 a = *(const bf16x8*)(sT + swzB(r0 + lr, kB, 256));
#pragma unroll
    for (int j = 0; j < 4; ++j) {
      bf16x8 b = *(const bf16x8*)(sW2 + swzB(cb + j * 16 + lr, kB, 256));
      acc2[j] = __builtin_amdgcn_mfma_f32_16x16x32_bf16(a, b, acc2[j], 0, 0, 0);
    }
  }
#pragma unroll
  for (int j = 0; j < 4; ++j) {
    int col = cb + j * 16 + lr;
    float bv = b2[col];
#pragma unroll
    for (int r = 0; r < 4; ++r) {
      int node = nb + r0 + grp * 4 + r;
      if (node < nN) out[(long)node * 128 + col] = acc2[j][r] + bv;
    }
  }
}

// ========================================================================
extern "C" void kernel_launch(void* const* d_in, const int* in_sizes, int n_in,
                              void* d_out, int out_size, void* d_ws, size_t ws_size,
                              hipStream_t stream) {
  const float* h   = (const float*)d_in[0];
  const int*   ei  = (const int*)d_in[1];
  const float* ew1 = (const float*)d_in[2];
  const float* eb1 = (const float*)d_in[3];
  const float* ew2 = (const float*)d_in[4];
  const float* eb2 = (const float*)d_in[5];
  const float* nw1 = (const float*)d_in[6];
  const float* nb1 = (const float*)d_in[7];
  const float* nw2 = (const float*)d_in[8];
  const float* nb2 = (const float*)d_in[9];
  float* out = (float*)d_out;

  const int E = in_sizes[1] / 2;            // 600000
  const int N = in_sizes[0] / 128;          // 50000
  const int NP = ((N + 255) / 256) * 256;   // 50176
  const int NB = NP / 256;                  // 196
  const int degInt4 = NP / 4;               // 12544

  // ---- ws layout (all offsets 16B-aligned) ----
  char* base = (char*)d_ws;
  short* W1t    = (short*)base;                    // 16384 bf16
  short* NW1t   = W1t + 16384;                     // 32768
  short* NW2t   = NW1t + 32768;                    // 16384
  float* c0     = (float*)(NW2t + 16384);          // 128
  int*   deg    = (int*)(c0 + 128);                // NP
  int*   cursor = deg + NP;                        // NP
  int*   rowptr = cursor + NP;                     // NP
  int*   bsums  = rowptr + NP;                     // 256
  int*   colS   = bsums + 256;                     // E
  size_t off    = (((size_t)((char*)(colS + E) - base)) + 15) & ~(size_t)15;
  unsigned short* Tb = (unsigned short*)(base + off);       // NP*128 bf16
  unsigned short* g  = Tb + (size_t)NP * 128;               // NP*128 bf16
  size_t needed = off + 2 * (size_t)NP * 256;

  if (ws_size >= needed) {
    // total prep items: 65664 + degInt4
    int prepBlocks = (65664 + degInt4 + 255) / 256;
    prep_all<<<prepBlocks, 256, 0, stream>>>(ew1, ew2, eb2, nw1, nw2,
                                             W1t, NW1t, NW2t, c0, deg, degInt4);
    hist_kernel<<<(E + 255) / 256, 256, 0, stream>>>(ei, deg, E);
    g_kernel<<<(N + 63) / 64, 256, 0, stream>>>(h, W1t, g, N);
    scan_local_kernel<<<NB, 256, 0, stream>>>(deg, cursor, bsums);
    scan_blocks_kernel<<<1, 256, 0, stream>>>(bsums, NB);
    finalize_kernel<<<NB, 256, 0, stream>>>(cursor, bsums, rowptr);
    scatter2_kernel<<<(E + 255) / 256, 256, 0, stream>>>(ei, cursor, colS, E);
    edge_agg_kernel<<<(N + 3) / 4, 256, 0, stream>>>(g, rowptr, deg, colS, eb1, Tb, N);
    node_kernel_new<<<(N + 63) / 64, 512, 0, stream>>>(h, Tb, nb1, nb2, NW1t, NW2t,
                                                       deg, c0, out, N);
    return;
  }

  // ---- fallback: per-edge atomics (needs only 160KB ws) ----
  short* wsS   = (short*)d_ws;
  short* fW1t  = wsS;
  short* fW2t  = wsS + 16384;
  short* fNW1t = wsS + 32768;
  short* fNW2t = wsS + 65536;
  hipMemsetAsync(d_out, 0, (size_t)out_size * sizeof(float), stream);
  prep_kernel_fb<<<320, 256, 0, stream>>>(ew1, ew2, nw1, nw2, wsS);
  edge_kernel_fb<<<(E + 127) / 128, 512, 0, stream>>>(h, ei, eb1, eb2, fW1t, fW2t, out, E);
  node_kernel_fb<<<(N + 63) / 64, 512, 0, stream>>>(h, out, nb1, nb2, fNW1t, fNW2t, out, N);
}

// Round 6
// 141.643 us; speedup vs baseline: 2.8573x; 1.0298x over previous
//
#include <hip/hip_runtime.h>
#include <hip/hip_bf16.h>

// GraphConv layer, R6.
//   g = h@e_w1 (bf16/node).  T[n] = sum_edges relu(g[n]+b1 - g[col])  (t-space aggregate).
//   out = relu(h@A + T@(e_w2@B) + deg*(e_b2@B) + n_b1)@n_w2 + n_b2   (folded node MLP).
// R6: node kernel 144->80KB LDS (A-frags from global, W2 from L2) -> 2 blocks/CU;
//     edge_agg dual-stream gather (2 outstanding row loads/group);
//     7-kernel chain (g+hist fused; scan_blocks+finalize fused).

typedef __attribute__((ext_vector_type(4))) float f32x4;
typedef __attribute__((ext_vector_type(8))) __bf16 bf16x8;
typedef __attribute__((ext_vector_type(4))) short s16x4;
typedef __attribute__((ext_vector_type(8))) unsigned short u16x8;

__device__ __forceinline__ short f2bf(float f) {
  unsigned x = __float_as_uint(f);
  x = (x + 0x7fffu + ((x >> 16) & 1u)) >> 16;
  return (short)x;
}
__device__ __forceinline__ float bf2f(unsigned short u) {
  return __uint_as_float(((unsigned)u) << 16);
}
// XOR swizzle on byte bits 4..6 within a row (G4 / m214 r268)
__device__ __forceinline__ int swzB(int row, int colByte, int strideB) {
  return row * strideB + (colByte ^ ((row & 7) << 4));
}

// ================= prep_all: weight prep + WB fold + zero deg =================
__global__ void prep_all(const float* __restrict__ ew1, const float* __restrict__ ew2,
                         const float* __restrict__ eb2, const float* __restrict__ nw1,
                         const float* __restrict__ nw2, short* __restrict__ W1t,
                         short* __restrict__ NW1t, short* __restrict__ NW2t,
                         float* __restrict__ c0, int* __restrict__ deg, int degInt4) {
  int idx = blockIdx.x * 256 + threadIdx.x;
  if (idx < 16384) {                        // W1t [128o][128k] <- e_w1
    int n = idx >> 7, k = idx & 127;
    W1t[idx] = f2bf(ew1[k * 128 + n]);
  } else if (idx < 32768) {                 // NW1t [128o][256k], k<128 <- n_w1[:128]
    int o = idx - 16384; int n = o >> 7, k = o & 127;
    NW1t[n * 256 + k] = f2bf(nw1[k * 128 + n]);
  } else if (idx < 49152) {                 // NW2t [128o][128k] <- n_w2
    int o = idx - 32768; int n = o >> 7, k = o & 127;
    NW2t[o] = f2bf(nw2[k * 128 + n]);
  } else if (idx < 65536) {                 // WB[kt][o] = e_w2[kt,:]@n_w1[128:,o] -> k=128+kt
    int o = idx - 49152; int ocol = o & 127, kt = o >> 7;
    float s = 0.f;
    for (int m = 0; m < 128; ++m) s += ew2[kt * 128 + m] * nw1[(128 + m) * 128 + ocol];
    NW1t[ocol * 256 + 128 + kt] = f2bf(s);
  } else if (idx < 65664) {                 // c0[o] = e_b2@n_w1[128:,o]
    int o = idx - 65536;
    float s = 0.f;
    for (int m = 0; m < 128; ++m) s += eb2[m] * nw1[(128 + m) * 128 + o];
    c0[o] = s;
  } else if (idx < 65664 + degInt4) {       // zero deg (int4 stores)
    ((int4*)deg)[idx - 65664] = (int4){0, 0, 0, 0};
  }
}

// ================= fused g = h@e_w1  +  hist(deg) =================
__global__ __launch_bounds__(256) void gh_kernel(
    const float* __restrict__ h, const short* __restrict__ W1t,
    unsigned short* __restrict__ gOut, int nN,
    const int* __restrict__ ei, int* __restrict__ deg, int nE, int gBlocks) {
  __shared__ __align__(16) char sW[32768];
  __shared__ __align__(16) char sO[16384];

  const int tid = threadIdx.x;
  if (blockIdx.x >= gBlocks) {
    // ---- hist part ----
    int e = (blockIdx.x - gBlocks) * 256 + tid;
    if (e < nE) atomicAdd(&deg[ei[e]], 1);
    return;
  }
  // ---- g part ----
  const int lane = tid & 63, wv = tid >> 6;
  const int lr = lane & 15, grp = lane >> 4;
  const int nb = blockIdx.x * 64;

#pragma unroll
  for (int i = 0; i < 8; ++i) {
    int c = i * 256 + tid;
    int n = c >> 4, kB = (c & 15) * 16;
    *(int4*)(sW + swzB(n, kB, 256)) = ((const int4*)W1t)[c];
  }
  bf16x8 afr[4];
  {
    int row = nb + wv * 16 + lr;
    int nd = (row < nN) ? row : 0;
    const float* hr = h + (long)nd * 128;
#pragma unroll
    for (int kk = 0; kk < 4; ++kk) {
      int k0 = kk * 32 + grp * 8;
      f32x4 a0 = *(const f32x4*)(hr + k0), a1 = *(const f32x4*)(hr + k0 + 4);
      union { bf16x8 v; short s[8]; } u;
      u.s[0] = f2bf(a0.x); u.s[1] = f2bf(a0.y); u.s[2] = f2bf(a0.z); u.s[3] = f2bf(a0.w);
      u.s[4] = f2bf(a1.x); u.s[5] = f2bf(a1.y); u.s[6] = f2bf(a1.z); u.s[7] = f2bf(a1.w);
      afr[kk] = u.v;
    }
  }
  __syncthreads();

  f32x4 acc[8];
#pragma unroll
  for (int j = 0; j < 8; ++j) acc[j] = (f32x4){0.f, 0.f, 0.f, 0.f};
#pragma unroll
  for (int kk = 0; kk < 4; ++kk) {
    int kB = (kk * 32 + grp * 8) * 2;
#pragma unroll
    for (int j = 0; j < 8; ++j) {
      bf16x8 b = *(const bf16x8*)(sW + swzB(j * 16 + lr, kB, 256));
      acc[j] = __builtin_amdgcn_mfma_f32_16x16x32_bf16(afr[kk], b, acc[j], 0, 0, 0);
    }
  }
#pragma unroll
  for (int j = 0; j < 8; ++j) {
    int col = j * 16 + lr;
#pragma unroll
    for (int r = 0; r < 4; ++r) {
      int row = wv * 16 + grp * 4 + r;
      *(short*)(sO + row * 256 + ((col * 2) ^ ((row & 7) << 4))) = f2bf(acc[j][r]);
    }
  }
  __syncthreads();
#pragma unroll
  for (int i = 0; i < 4; ++i) {
    int c = i * 256 + tid;
    int row = c >> 4;
    int node = nb + row;
    if (node < nN) {
      int4 v = *(const int4*)(sO + row * 256 + (((c & 15) * 16) ^ ((row & 7) << 4)));
      ((int4*)gOut)[node * 16 + (c & 15)] = v;
    }
  }
}

// ================= scan =================
__global__ void scan_local_kernel(const int* __restrict__ deg, int* __restrict__ cursor,
                                  int* __restrict__ bsums) {
  __shared__ int s[256];
  int i = threadIdx.x, gidx = blockIdx.x * 256 + i;
  int v = deg[gidx];
  s[i] = v; __syncthreads();
#pragma unroll
  for (int off = 1; off < 256; off <<= 1) {
    int t = (i >= off) ? s[i - off] : 0;
    __syncthreads();
    s[i] += t;
    __syncthreads();
  }
  cursor[gidx] = s[i] - v;
  if (i == 255) bsums[blockIdx.x] = s[255];
}

// each block scans all bsums in LDS (redundant, cheap) and applies its chunk offset
__global__ void finalize_scan_kernel(int* __restrict__ cursor, const int* __restrict__ bsums,
                                     int* __restrict__ rowptr, int nb) {
  __shared__ int s[256];
  int i = threadIdx.x;
  s[i] = (i < nb) ? bsums[i] : 0;
  __syncthreads();
#pragma unroll
  for (int off = 1; off < 256; off <<= 1) {
    int t = (i >= off) ? s[i - off] : 0;
    __syncthreads();
    s[i] += t;
    __syncthreads();
  }
  int b = blockIdx.x;
  int offv = (b == 0) ? 0 : s[b - 1];
  int gidx = b * 256 + i;
  int v = cursor[gidx] + offv;
  cursor[gidx] = v;
  rowptr[gidx] = v;
}

__global__ void scatter2_kernel(const int* __restrict__ ei, int* __restrict__ cursor,
                                int* __restrict__ colS, int nE) {
  int e = blockIdx.x * 256 + threadIdx.x;
  if (e < nE) {
    int r = ei[e];
    int pos = atomicAdd(&cursor[r], 1);
    colS[pos] = ei[nE + e];
  }
}

// ================= edge aggregate: Tb[n] = bf16( sum relu(g[n]+b1 - g[col]) ) ==========
__global__ __launch_bounds__(256) void edge_agg_kernel(
    const unsigned short* __restrict__ g, const int* __restrict__ rowptr,
    const int* __restrict__ deg, const int* __restrict__ colS,
    const float* __restrict__ b1, unsigned short* __restrict__ Tb, int nN) {
  const int tid = threadIdx.x;
  const int lane = tid & 63, wv = tid >> 6;
  const int lr = lane & 15, grp = lane >> 4;
  const int n = blockIdx.x * 4 + wv;
  if (n >= nN) return;

  const int rp = rowptr[n], dg = deg[n];
  u16x8 gu = *(const u16x8*)(g + (long)n * 128 + lr * 8);
  f32x4 b1a = *(const f32x4*)(b1 + lr * 8);
  f32x4 b1b = *(const f32x4*)(b1 + lr * 8 + 4);
  float gnb[8];
#pragma unroll
  for (int j = 0; j < 4; ++j) gnb[j] = bf2f(gu[j]) + b1a[j];
#pragma unroll
  for (int j = 0; j < 4; ++j) gnb[4 + j] = bf2f(gu[4 + j]) + b1b[j];

  float acc[8] = {0.f, 0.f, 0.f, 0.f, 0.f, 0.f, 0.f, 0.f};
  int i = grp;
  // dual-stream: two g-row loads in flight per 16-lane group
  for (; i + 4 < dg; i += 8) {
    int ca = colS[rp + i], cb = colS[rp + i + 4];
    u16x8 ga = *(const u16x8*)(g + (long)ca * 128 + lr * 8);
    u16x8 gb = *(const u16x8*)(g + (long)cb * 128 + lr * 8);
#pragma unroll
    for (int j = 0; j < 8; ++j) {
      float d0 = gnb[j] - bf2f(ga[j]);
      float d1 = gnb[j] - bf2f(gb[j]);
      acc[j] += (d0 > 0.f ? d0 : 0.f) + (d1 > 0.f ? d1 : 0.f);
    }
  }
  if (i < dg) {
    int ca = colS[rp + i];
    u16x8 ga = *(const u16x8*)(g + (long)ca * 128 + lr * 8);
#pragma unroll
    for (int j = 0; j < 8; ++j) {
      float d0 = gnb[j] - bf2f(ga[j]);
      acc[j] += (d0 > 0.f ? d0 : 0.f);
    }
  }
#pragma unroll
  for (int j = 0; j < 8; ++j) acc[j] += __shfl_xor(acc[j], 16);
#pragma unroll
  for (int j = 0; j < 8; ++j) acc[j] += __shfl_xor(acc[j], 32);

  if (grp == 0) {
    union { u16x8 v; unsigned short s[8]; } o;
#pragma unroll
    for (int j = 0; j < 8; ++j) o.s[j] = (unsigned short)f2bf(acc[j]);
    *(u16x8*)(Tb + (long)n * 128 + lr * 8) = o.v;
  }
}

// ===== node kernel: out = relu(h@A + Tb@WB + deg*c0 + nb1)@NW2 + nb2 (80KB LDS) =====
__global__ __launch_bounds__(512, 4) void node_kernel_new(
    const float* __restrict__ h, const unsigned short* __restrict__ Tb,
    const float* __restrict__ b1, const float* __restrict__ b2,
    const short* __restrict__ W1t, const short* __restrict__ W2t,
    const int* __restrict__ deg, const float* __restrict__ c0,
    float* __restrict__ out, int nN) {
  __shared__ __align__(16) char sW1[65536];   // NW1t [128o][256k] swizzled
  __shared__ __align__(16) char sT[16384];    // relu stage [64][128] bf16 swizzled

  const int tid = threadIdx.x;
  const int lane = tid & 63, wv = tid >> 6;
  const int lr = lane & 15, grp = lane >> 4;
  const int nb = blockIdx.x * 64;
  const int r0 = (wv >> 1) * 16;
  const int cb = (wv & 1) * 64;

  // stage W1 (4096 int4 chunks)
#pragma unroll
  for (int i = 0; i < 8; ++i) {
    int c = i * 512 + tid;
    int n = c >> 5, kB = (c & 31) * 16;
    *(int4*)(sW1 + swzB(n, kB, 512)) = ((const int4*)W1t)[c];
  }
  // A-fragments direct from global: z = [bf16(h) | Tb], row = nb+r0+lr, K=256
  bf16x8 afr[8];
  {
    int node = nb + r0 + lr;
    bool ok = node < nN;
    int nd = ok ? node : 0;
    const float* hr = h + (long)nd * 128;
    const unsigned short* tr = Tb + (long)nd * 128;
#pragma unroll
    for (int kk = 0; kk < 4; ++kk) {
      int k0 = kk * 32 + grp * 8;
      f32x4 a0 = *(const f32x4*)(hr + k0), a1 = *(const f32x4*)(hr + k0 + 4);
      union { bf16x8 v; short s[8]; } u;
      u.s[0] = f2bf(a0.x); u.s[1] = f2bf(a0.y); u.s[2] = f2bf(a0.z); u.s[3] = f2bf(a0.w);
      u.s[4] = f2bf(a1.x); u.s[5] = f2bf(a1.y); u.s[6] = f2bf(a1.z); u.s[7] = f2bf(a1.w);
      if (!ok) u.v = (bf16x8)(__bf16)0.f;
      afr[kk] = u.v;
    }
#pragma unroll
    for (int kk = 0; kk < 4; ++kk) {
      int k0 = kk * 32 + grp * 8;
      union { bf16x8 v; u16x8 u; } w;
      w.u = *(const u16x8*)(tr + k0);
      if (!ok) w.v = (bf16x8)(__bf16)0.f;
      afr[4 + kk] = w.v;
    }
  }
  __syncthreads();

  // layer 1: wave tile 16 rows x 64 cols, K=256
  f32x4 acc[4];
#pragma unroll
  for (int j = 0; j < 4; ++j) acc[j] = (f32x4){0.f, 0.f, 0.f, 0.f};
#pragma unroll
  for (int kk = 0; kk < 8; ++kk) {
    int kB = (kk * 32 + grp * 8) * 2;
#pragma unroll
    for (int j = 0; j < 4; ++j) {
      bf16x8 b = *(const bf16x8*)(sW1 + swzB(cb + j * 16 + lr, kB, 512));
      acc[j] = __builtin_amdgcn_mfma_f32_16x16x32_bf16(afr[kk], b, acc[j], 0, 0, 0);
    }
  }
  float degs[4];
#pragma unroll
  for (int r = 0; r < 4; ++r) {
    int node = nb + r0 + grp * 4 + r;
    degs[r] = (float)deg[node];               // deg zeroed through NP
  }
#pragma unroll
  for (int j = 0; j < 4; ++j) {
    int col = cb + j * 16 + lr;
    float bv = b1[col];
    float c0v = c0[col];
#pragma unroll
    for (int r = 0; r < 4; ++r) {
      int row = r0 + grp * 4 + r;
      float v = acc[j][r] + bv + degs[r] * c0v;
      v = v > 0.f ? v : 0.f;
      *(short*)(sT + swzB(row, col * 2, 256)) = f2bf(v);
    }
  }
  __syncthreads();

  // layer 2: A from sT, B direct from global NW2t (L1/L2-resident, 32KB)
  f32x4 acc2[4];
#pragma unroll
  for (int j = 0; j < 4; ++j) acc2[j] = (f32x4){0.f, 0.f, 0.f, 0.f};
#pragma unroll
  for (int kk = 0; kk < 4; ++kk) {
    int kB = (kk * 32 + grp * 8) * 2;
    bf16x8 a = *(const bf16x8*)(sT + swzB(r0 + lr, kB, 256));
#pragma unroll
    for (int j = 0; j < 4; ++j) {
      bf16x8 b = *(const bf16x8*)(W2t + (cb + j * 16 + lr) * 128 + kk * 32 + grp * 8);
      acc2[j] = __builtin_amdgcn_mfma_f32_16x16x32_bf16(a, b, acc2[j], 0, 0, 0);
    }
  }
#pragma unroll
  for (int j = 0; j < 4; ++j) {
    int col = cb + j * 16 + lr;
    float bv = b2[col];
#pragma unroll
    for (int r = 0; r < 4; ++r) {
      int node = nb + r0 + grp * 4 + r;
      if (node < nN) out[(long)node * 128 + col] = acc2[j][r] + bv;
    }
  }
}

// ========================================================================
// ================= minimal fallback (per-edge atomics, 160KB ws) ========
// ========================================================================
__global__ void prep_kernel_fb(const float* __restrict__ ew1, const float* __restrict__ ew2,
                               const float* __restrict__ nw1, const float* __restrict__ nw2,
                               short* __restrict__ wsS) {
  int idx = blockIdx.x * 256 + threadIdx.x;
  if (idx < 16384) {
    int n = idx >> 7, k = idx & 127;
    wsS[idx] = f2bf(ew1[k * 128 + n]);
  } else if (idx < 32768) {
    int o = idx - 16384; int n = o >> 7, k = o & 127;
    wsS[idx] = f2bf(ew2[k * 128 + n]);
  } else if (idx < 65536) {
    int o = idx - 32768; int n = o >> 8, k = o & 255;
    wsS[idx] = f2bf(nw1[k * 128 + n]);
  } else if (idx < 81920) {
    int o = idx - 65536; int n = o >> 7, k = o & 127;
    wsS[idx] = f2bf(nw2[k * 128 + n]);
  }
}

__global__ __launch_bounds__(512) void edge_kernel_fb(
    const float* __restrict__ h, const int* __restrict__ ei,
    const float* __restrict__ b1, const float* __restrict__ b2,
    const short* __restrict__ W1t, const short* __restrict__ W2t,
    float* __restrict__ agg, int nE) {
  __shared__ __align__(16) char sW1[32768];
  __shared__ __align__(16) char sW2[32768];
  __shared__ __align__(16) char sT[32768];

  const int tid = threadIdx.x;
  const int lane = tid & 63, wv = tid >> 6;
  const int lr = lane & 15, grp = lane >> 4;
  const int eb = blockIdx.x * 128;
  const int* rowI = ei;
  const int* colI = ei + nE;

#pragma unroll
  for (int i = 0; i < 4; ++i) {
    int c = i * 512 + tid;
    int n = c >> 4, kB = (c & 15) * 16;
    *(int4*)(sW1 + swzB(n, kB, 256)) = ((const int4*)W1t)[c];
    *(int4*)(sW2 + swzB(n, kB, 256)) = ((const int4*)W2t)[c];
  }
  bf16x8 afr[4];
  {
    int slot = eb + wv * 16 + lr;
    int r = 0, cc = 0;
    if (slot < nE) { r = rowI[slot]; cc = colI[slot]; }
    const float* hr = h + (long)r * 128;
    const float* hc = h + (long)cc * 128;
#pragma unroll
    for (int kk = 0; kk < 4; ++kk) {
      int k0 = kk * 32 + grp * 8;
      f32x4 a0 = *(const f32x4*)(hr + k0), a1 = *(const f32x4*)(hr + k0 + 4);
      f32x4 c0_ = *(const f32x4*)(hc + k0), c1 = *(const f32x4*)(hc + k0 + 4);
      union { bf16x8 v; short s[8]; } u;
      u.s[0] = f2bf(a0.x - c0_.x); u.s[1] = f2bf(a0.y - c0_.y);
      u.s[2] = f2bf(a0.z - c0_.z); u.s[3] = f2bf(a0.w - c0_.w);
      u.s[4] = f2bf(a1.x - c1.x); u.s[5] = f2bf(a1.y - c1.y);
      u.s[6] = f2bf(a1.z - c1.z); u.s[7] = f2bf(a1.w - c1.w);
      afr[kk] = u.v;
    }
  }
  __syncthreads();

  f32x4 acc[8];
#pragma unroll
  for (int j = 0; j < 8; ++j) acc[j] = (f32x4){0.f, 0.f, 0.f, 0.f};
#pragma unroll
  for (int kk = 0; kk < 4; ++kk) {
    int kB = (kk * 32 + grp * 8) * 2;
#pragma unroll
    for (int j = 0; j < 8; ++j) {
      bf16x8 b = *(const bf16x8*)(sW1 + swzB(j * 16 + lr, kB, 256));
      acc[j] = __builtin_amdgcn_mfma_f32_16x16x32_bf16(afr[kk], b, acc[j], 0, 0, 0);
    }
  }
#pragma unroll
  for (int j = 0; j < 8; ++j) {
    int col = j * 16 + lr;
    float bv = b1[col];
#pragma unroll
    for (int r = 0; r < 4; ++r) {
      int row = wv * 16 + grp * 4 + r;
      float v = acc[j][r] + bv;
      v = v > 0.f ? v : 0.f;
      *(short*)(sT + swzB(row, col * 2, 256)) = f2bf(v);
    }
  }
  __syncthreads();

  f32x4 acc2[8];
#pragma unroll
  for (int j = 0; j < 8; ++j) acc2[j] = (f32x4){0.f, 0.f, 0.f, 0.f};
#pragma unroll
  for (int kk = 0; kk < 4; ++kk) {
    int kB = (kk * 32 + grp * 8) * 2;
    bf16x8 a = *(const bf16x8*)(sT + swzB(wv * 16 + lr, kB, 256));
#pragma unroll
    for (int j = 0; j < 8; ++j) {
      bf16x8 b = *(const bf16x8*)(sW2 + swzB(j * 16 + lr, kB, 256));
      acc2[j] = __builtin_amdgcn_mfma_f32_16x16x32_bf16(a, b, acc2[j], 0, 0, 0);
    }
  }
  int nd[4]; bool okr[4];
#pragma unroll
  for (int r = 0; r < 4; ++r) {
    int e = eb + wv * 16 + grp * 4 + r;
    okr[r] = e < nE;
    nd[r] = okr[r] ? rowI[e] : 0;
  }
#pragma unroll
  for (int j = 0; j < 8; ++j) {
    int col = j * 16 + lr;
    float bv = b2[col];
#pragma unroll
    for (int r = 0; r < 4; ++r) {
      if (okr[r]) atomicAdd(agg + (long)nd[r] * 128 + col, acc2[j][r] + bv);
    }
  }
}

__global__ __launch_bounds__(512) void node_kernel_fb(
    const float* __restrict__ h, const float* agg,
    const float* __restrict__ b1, const float* __restrict__ b2,
    const short* __restrict__ W1t, const short* __restrict__ W2t,
    float* out, int nN) {
  __shared__ __align__(16) char sZ[32768];
  __shared__ __align__(16) char sW1[65536];
  __shared__ __align__(16) char sW2[32768];
  __shared__ __align__(16) char sT[16384];

  const int tid = threadIdx.x;
  const int lane = tid & 63, wv = tid >> 6;
  const int lr = lane & 15, grp = lane >> 4;
  const int nb = blockIdx.x * 64;

#pragma unroll
  for (int i = 0; i < 8; ++i) {
    int c = i * 512 + tid;
    int n = c >> 5, kB = (c & 31) * 16;
    *(int4*)(sW1 + swzB(n, kB, 512)) = ((const int4*)W1t)[c];
  }
#pragma unroll
  for (int i = 0; i < 4; ++i) {
    int c = i * 512 + tid;
    int n = c >> 4, kB = (c & 15) * 16;
    *(int4*)(sW2 + swzB(n, kB, 256)) = ((const int4*)W2t)[c];
  }
  {
    int i = tid >> 3;
    int node = nb + i;
    bool ok = node < nN;
    int nd = ok ? node : 0;
#pragma unroll
    for (int it = 0; it < 8; ++it) {
      int c4 = (tid & 7) + it * 8;
      int col = c4 * 4;
      f32x4 v;
      if (col < 128) v = *(const f32x4*)(h + (long)nd * 128 + col);
      else           v = *(const f32x4*)(agg + (long)nd * 128 + (col - 128));
      if (!ok) v = (f32x4){0.f, 0.f, 0.f, 0.f};
      s16x4 p;
      p.x = f2bf(v.x); p.y = f2bf(v.y); p.z = f2bf(v.z); p.w = f2bf(v.w);
      *(s16x4*)(sZ + swzB(i, col * 2, 512)) = p;
    }
  }
  __syncthreads();

  const int r0 = (wv >> 1) * 16;
  const int cb = (wv & 1) * 64;
  f32x4 acc[4];
#pragma unroll
  for (int j = 0; j < 4; ++j) acc[j] = (f32x4){0.f, 0.f, 0.f, 0.f};
#pragma unroll
  for (int kk = 0; kk < 8; ++kk) {
    int kB = (kk * 32 + grp * 8) * 2;
    bf16x8 a = *(const bf16x8*)(sZ + swzB(r0 + lr, kB, 512));
#pragma unroll
    for (int j = 0; j < 4; ++j) {
      bf16x8 b = *(const bf16x8*)(sW1 + swzB(cb + j * 16 + lr, kB, 512));
      acc[j] = __builtin_amdgcn_mfma_f32_16x16x32_bf16(a, b, acc[j], 0, 0, 0);
    }
  }
#pragma unroll
  for (int j = 0; j < 4; ++j) {
    int col = cb + j * 16 + lr;
    float bv = b1[col];
#pragma unroll
    for (int r = 0; r < 4; ++r) {
      int row = r0 + grp * 4 + r;
      float v = acc[j][r] + bv;
      v = v > 0.f ? v : 0.f;
      *(short*)(sT + swzB(row, col * 2, 256)) = f2bf(v);
    }
  }
  __syncthreads();

  f32x4 acc2[4];
#pragma unroll
  for (int j = 0; j < 4; ++j) acc2[j] = (f32x4){0.f, 0.f, 0.f, 0.f};
#pragma unroll
  for (int kk = 0; kk < 4; ++kk) {
    int kB = (kk * 32 + grp * 8) * 2;
    bf16x8 a = *(const bf16x8*)(sT + swzB(r0 + lr, kB, 256));
#pragma unroll
    for (int j = 0; j < 4; ++j) {
      bf16x8 b = *(const bf16x8*)(sW2 + swzB(cb + j * 16 + lr, kB, 256));
      acc2[j] = __builtin_amdgcn_mfma_f32_16x16x32_bf16(a, b, acc2[j], 0, 0, 0);
    }
  }
#pragma unroll
  for (int j = 0; j < 4; ++j) {
    int col = cb + j * 16 + lr;
    float bv = b2[col];
#pragma unroll
    for (int r = 0; r < 4; ++r) {
      int node = nb + r0 + grp * 4 + r;
      if (node < nN) out[(long)node * 128 + col] = acc2[j][r] + bv;
    }
  }
}

// ========================================================================
extern "C" void kernel_launch(void* const* d_in, const int* in_sizes, int n_in,
                              void* d_out, int out_size, void* d_ws, size_t ws_size,
                              hipStream_t stream) {
  const float* h   = (const float*)d_in[0];
  const int*   ei  = (const int*)d_in[1];
  const float* ew1 = (const float*)d_in[2];
  const float* eb1 = (const float*)d_in[3];
  const float* ew2 = (const float*)d_in[4];
  const float* eb2 = (const float*)d_in[5];
  const float* nw1 = (const float*)d_in[6];
  const float* nb1 = (const float*)d_in[7];
  const float* nw2 = (const float*)d_in[8];
  const float* nb2 = (const float*)d_in[9];
  float* out = (float*)d_out;

  const int E = in_sizes[1] / 2;            // 600000
  const int N = in_sizes[0] / 128;          // 50000
  const int NP = ((N + 255) / 256) * 256;   // 50176
  const int NB = NP / 256;                  // 196
  const int degInt4 = NP / 4;

  // ---- ws layout ----
  char* base = (char*)d_ws;
  short* W1t    = (short*)base;                    // 16384 bf16
  short* NW1t   = W1t + 16384;                     // 32768
  short* NW2t   = NW1t + 32768;                    // 16384
  float* c0     = (float*)(NW2t + 16384);          // 128
  int*   deg    = (int*)(c0 + 128);                // NP
  int*   cursor = deg + NP;                        // NP
  int*   rowptr = cursor + NP;                     // NP
  int*   bsums  = rowptr + NP;                     // 256
  int*   colS   = bsums + 256;                     // E
  size_t off    = (((size_t)((char*)(colS + E) - base)) + 15) & ~(size_t)15;
  unsigned short* Tb = (unsigned short*)(base + off);       // NP*128 bf16
  unsigned short* g  = Tb + (size_t)NP * 128;               // NP*128 bf16
  size_t needed = off + 2 * (size_t)NP * 256;

  if (ws_size >= needed) {
    const int gBlocks = (N + 63) / 64;
    const int histBlocks = (E + 255) / 256;
    int prepBlocks = (65664 + degInt4 + 255) / 256;
    prep_all<<<prepBlocks, 256, 0, stream>>>(ew1, ew2, eb2, nw1, nw2,
                                             W1t, NW1t, NW2t, c0, deg, degInt4);
    gh_kernel<<<gBlocks + histBlocks, 256, 0, stream>>>(h, W1t, g, N, ei, deg, E, gBlocks);
    scan_local_kernel<<<NB, 256, 0, stream>>>(deg, cursor, bsums);
    finalize_scan_kernel<<<NB, 256, 0, stream>>>(cursor, bsums, rowptr, NB);
    scatter2_kernel<<<(E + 255) / 256, 256, 0, stream>>>(ei, cursor, colS, E);
    edge_agg_kernel<<<(N + 3) / 4, 256, 0, stream>>>(g, rowptr, deg, colS, eb1, Tb, N);
    node_kernel_new<<<(N + 63) / 64, 512, 0, stream>>>(h, Tb, nb1, nb2, NW1t, NW2t,
                                                       deg, c0, out, N);
    return;
  }

  // ---- fallback: per-edge atomics (needs only 160KB ws) ----
  short* wsS   = (short*)d_ws;
  short* fW1t  = wsS;
  short* fW2t  = wsS + 16384;
  short* fNW1t = wsS + 32768;
  short* fNW2t = wsS + 65536;
  hipMemsetAsync(d_out, 0, (size_t)out_size * sizeof(float), stream);
  prep_kernel_fb<<<320, 256, 0, stream>>>(ew1, ew2, nw1, nw2, wsS);
  edge_kernel_fb<<<(E + 127) / 128, 512, 0, stream>>>(h, ei, eb1, eb2, fW1t, fW2t, out, E);
  node_kernel_fb<<<(N + 63) / 64, 512, 0, stream>>>(h, out, nb1, nb2, fNW1t, fNW2t, out, N);
}

// Round 7
// 137.936 us; speedup vs baseline: 2.9341x; 1.0269x over previous
//
#include <hip/hip_runtime.h>
#include <hip/hip_bf16.h>

// GraphConv layer, R7.
//   g = h@e_w1 (bf16/node).  T[n] = sum_edges relu(g[n]+b1 - g[col])  (t-space aggregate).
//   out = relu(h@A + T@(e_w2@B) + deg*(e_b2@B) + n_b1)@n_w2 + n_b2   (folded node MLP).
// R7: edge_agg fused INTO node kernel (T gathered in-register -> sT LDS; no Tb round-trip,
//     W1 staging + h loads overlap gather latency). 6-kernel chain.

typedef __attribute__((ext_vector_type(4))) float f32x4;
typedef __attribute__((ext_vector_type(8))) __bf16 bf16x8;
typedef __attribute__((ext_vector_type(4))) short s16x4;
typedef __attribute__((ext_vector_type(8))) unsigned short u16x8;

__device__ __forceinline__ short f2bf(float f) {
  unsigned x = __float_as_uint(f);
  x = (x + 0x7fffu + ((x >> 16) & 1u)) >> 16;
  return (short)x;
}
__device__ __forceinline__ float bf2f(unsigned short u) {
  return __uint_as_float(((unsigned)u) << 16);
}
// XOR swizzle on byte bits 4..6 within a row (G4 / m214 r268)
__device__ __forceinline__ int swzB(int row, int colByte, int strideB) {
  return row * strideB + (colByte ^ ((row & 7) << 4));
}

// ================= prep_all: weight prep + WB fold + zero deg =================
__global__ void prep_all(const float* __restrict__ ew1, const float* __restrict__ ew2,
                         const float* __restrict__ eb2, const float* __restrict__ nw1,
                         const float* __restrict__ nw2, short* __restrict__ W1t,
                         short* __restrict__ NW1t, short* __restrict__ NW2t,
                         float* __restrict__ c0, int* __restrict__ deg, int degInt4) {
  int idx = blockIdx.x * 256 + threadIdx.x;
  if (idx < 16384) {                        // W1t [128o][128k] <- e_w1
    int n = idx >> 7, k = idx & 127;
    W1t[idx] = f2bf(ew1[k * 128 + n]);
  } else if (idx < 32768) {                 // NW1t [128o][256k], k<128 <- n_w1[:128]
    int o = idx - 16384; int n = o >> 7, k = o & 127;
    NW1t[n * 256 + k] = f2bf(nw1[k * 128 + n]);
  } else if (idx < 49152) {                 // NW2t [128o][128k] <- n_w2
    int o = idx - 32768; int n = o >> 7, k = o & 127;
    NW2t[o] = f2bf(nw2[k * 128 + n]);
  } else if (idx < 65536) {                 // WB[kt][o] = e_w2[kt,:]@n_w1[128:,o] -> k=128+kt
    int o = idx - 49152; int ocol = o & 127, kt = o >> 7;
    float s = 0.f;
    for (int m = 0; m < 128; ++m) s += ew2[kt * 128 + m] * nw1[(128 + m) * 128 + ocol];
    NW1t[ocol * 256 + 128 + kt] = f2bf(s);
  } else if (idx < 65664) {                 // c0[o] = e_b2@n_w1[128:,o]
    int o = idx - 65536;
    float s = 0.f;
    for (int m = 0; m < 128; ++m) s += eb2[m] * nw1[(128 + m) * 128 + o];
    c0[o] = s;
  } else if (idx < 65664 + degInt4) {       // zero deg (int4 stores)
    ((int4*)deg)[idx - 65664] = (int4){0, 0, 0, 0};
  }
}

// ================= fused g = h@e_w1  +  hist(deg) =================
__global__ __launch_bounds__(256) void gh_kernel(
    const float* __restrict__ h, const short* __restrict__ W1t,
    unsigned short* __restrict__ gOut, int nN,
    const int* __restrict__ ei, int* __restrict__ deg, int nE, int gBlocks) {
  __shared__ __align__(16) char sW[32768];
  __shared__ __align__(16) char sO[16384];

  const int tid = threadIdx.x;
  if (blockIdx.x >= gBlocks) {
    int e = (blockIdx.x - gBlocks) * 256 + tid;
    if (e < nE) atomicAdd(&deg[ei[e]], 1);
    return;
  }
  const int lane = tid & 63, wv = tid >> 6;
  const int lr = lane & 15, grp = lane >> 4;
  const int nb = blockIdx.x * 64;

#pragma unroll
  for (int i = 0; i < 8; ++i) {
    int c = i * 256 + tid;
    int n = c >> 4, kB = (c & 15) * 16;
    *(int4*)(sW + swzB(n, kB, 256)) = ((const int4*)W1t)[c];
  }
  bf16x8 afr[4];
  {
    int row = nb + wv * 16 + lr;
    int nd = (row < nN) ? row : 0;
    const float* hr = h + (long)nd * 128;
#pragma unroll
    for (int kk = 0; kk < 4; ++kk) {
      int k0 = kk * 32 + grp * 8;
      f32x4 a0 = *(const f32x4*)(hr + k0), a1 = *(const f32x4*)(hr + k0 + 4);
      union { bf16x8 v; short s[8]; } u;
      u.s[0] = f2bf(a0.x); u.s[1] = f2bf(a0.y); u.s[2] = f2bf(a0.z); u.s[3] = f2bf(a0.w);
      u.s[4] = f2bf(a1.x); u.s[5] = f2bf(a1.y); u.s[6] = f2bf(a1.z); u.s[7] = f2bf(a1.w);
      afr[kk] = u.v;
    }
  }
  __syncthreads();

  f32x4 acc[8];
#pragma unroll
  for (int j = 0; j < 8; ++j) acc[j] = (f32x4){0.f, 0.f, 0.f, 0.f};
#pragma unroll
  for (int kk = 0; kk < 4; ++kk) {
    int kB = (kk * 32 + grp * 8) * 2;
#pragma unroll
    for (int j = 0; j < 8; ++j) {
      bf16x8 b = *(const bf16x8*)(sW + swzB(j * 16 + lr, kB, 256));
      acc[j] = __builtin_amdgcn_mfma_f32_16x16x32_bf16(afr[kk], b, acc[j], 0, 0, 0);
    }
  }
#pragma unroll
  for (int j = 0; j < 8; ++j) {
    int col = j * 16 + lr;
#pragma unroll
    for (int r = 0; r < 4; ++r) {
      int row = wv * 16 + grp * 4 + r;
      *(short*)(sO + row * 256 + ((col * 2) ^ ((row & 7) << 4))) = f2bf(acc[j][r]);
    }
  }
  __syncthreads();
#pragma unroll
  for (int i = 0; i < 4; ++i) {
    int c = i * 256 + tid;
    int row = c >> 4;
    int node = nb + row;
    if (node < nN) {
      int4 v = *(const int4*)(sO + row * 256 + (((c & 15) * 16) ^ ((row & 7) << 4)));
      ((int4*)gOut)[node * 16 + (c & 15)] = v;
    }
  }
}

// ================= scan =================
__global__ void scan_local_kernel(const int* __restrict__ deg, int* __restrict__ cursor,
                                  int* __restrict__ bsums) {
  __shared__ int s[256];
  int i = threadIdx.x, gidx = blockIdx.x * 256 + i;
  int v = deg[gidx];
  s[i] = v; __syncthreads();
#pragma unroll
  for (int off = 1; off < 256; off <<= 1) {
    int t = (i >= off) ? s[i - off] : 0;
    __syncthreads();
    s[i] += t;
    __syncthreads();
  }
  cursor[gidx] = s[i] - v;
  if (i == 255) bsums[blockIdx.x] = s[255];
}

__global__ void finalize_scan_kernel(int* __restrict__ cursor, const int* __restrict__ bsums,
                                     int* __restrict__ rowptr, int nb) {
  __shared__ int s[256];
  int i = threadIdx.x;
  s[i] = (i < nb) ? bsums[i] : 0;
  __syncthreads();
#pragma unroll
  for (int off = 1; off < 256; off <<= 1) {
    int t = (i >= off) ? s[i - off] : 0;
    __syncthreads();
    s[i] += t;
    __syncthreads();
  }
  int b = blockIdx.x;
  int offv = (b == 0) ? 0 : s[b - 1];
  int gidx = b * 256 + i;
  int v = cursor[gidx] + offv;
  cursor[gidx] = v;
  rowptr[gidx] = v;
}

__global__ void scatter2_kernel(const int* __restrict__ ei, int* __restrict__ cursor,
                                int* __restrict__ colS, int nE) {
  int e = blockIdx.x * 256 + threadIdx.x;
  if (e < nE) {
    int r = ei[e];
    int pos = atomicAdd(&cursor[r], 1);
    colS[pos] = ei[nE + e];
  }
}

// ===== fused agg+node: gather T in-reg -> sT; out = relu(h@A + T@WB + deg*c0 + nb1)@NW2 + nb2
__global__ __launch_bounds__(512, 4) void agg_node_kernel(
    const float* __restrict__ h, const unsigned short* __restrict__ g,
    const int* __restrict__ rowptr, const int* __restrict__ deg,
    const int* __restrict__ colS, const float* __restrict__ eb1,
    const float* __restrict__ b1, const float* __restrict__ b2,
    const short* __restrict__ NW1t, const short* __restrict__ NW2t,
    const float* __restrict__ c0, float* __restrict__ out, int nN) {
  __shared__ __align__(16) char sW1[65536];   // NW1t [128o][256k] swizzled
  __shared__ __align__(16) char sT[16384];    // T (bf16) then relu stage, [64][128] swizzled

  const int tid = threadIdx.x;
  const int lane = tid & 63, wv = tid >> 6;
  const int lr = lane & 15, grp = lane >> 4;
  const int nb = blockIdx.x * 64;
  const int r0 = (wv >> 1) * 16;
  const int cb = (wv & 1) * 64;

  // ---- stage W1 (issue first; completes by first barrier) ----
#pragma unroll
  for (int i = 0; i < 8; ++i) {
    int c = i * 512 + tid;
    int n = c >> 5, kB = (c & 31) * 16;
    *(int4*)(sW1 + swzB(n, kB, 512)) = ((const int4*)NW1t)[c];
  }

  // ---- gather T: thread owns node nb+(tid>>3), dims (tid&7)*16 .. +16 ----
  {
    int gi = tid >> 3;                   // 0..63
    int gn = nb + gi;
    bool gok = gn < nN;
    int nd = gok ? gn : 0;
    int rp = rowptr[nd];
    int dgv = gok ? deg[nd] : 0;
    int d0 = (tid & 7) * 16;

    float gnb[16];
    {
      u16x8 s0 = *(const u16x8*)(g + (long)nd * 128 + d0);
      u16x8 s1 = *(const u16x8*)(g + (long)nd * 128 + d0 + 8);
      f32x4 e0 = *(const f32x4*)(eb1 + d0),     e1 = *(const f32x4*)(eb1 + d0 + 4);
      f32x4 e2 = *(const f32x4*)(eb1 + d0 + 8), e3 = *(const f32x4*)(eb1 + d0 + 12);
#pragma unroll
      for (int j = 0; j < 4; ++j) {
        gnb[j]      = bf2f(s0[j])     + e0[j];
        gnb[4 + j]  = bf2f(s0[4 + j]) + e1[j];
        gnb[8 + j]  = bf2f(s1[j])     + e2[j];
        gnb[12 + j] = bf2f(s1[4 + j]) + e3[j];
      }
    }
    float tac[16];
#pragma unroll
    for (int j = 0; j < 16; ++j) tac[j] = 0.f;

    int i = 0;
    for (; i + 1 < dgv; i += 2) {        // 2-edge unroll: 4 loads in flight
      int ca = colS[rp + i], cb2 = colS[rp + i + 1];
      u16x8 a0 = *(const u16x8*)(g + (long)ca * 128 + d0);
      u16x8 a1 = *(const u16x8*)(g + (long)ca * 128 + d0 + 8);
      u16x8 b0 = *(const u16x8*)(g + (long)cb2 * 128 + d0);
      u16x8 b1v = *(const u16x8*)(g + (long)cb2 * 128 + d0 + 8);
#pragma unroll
      for (int j = 0; j < 8; ++j) {
        float da = gnb[j] - bf2f(a0[j]);
        float db = gnb[j] - bf2f(b0[j]);
        tac[j] += (da > 0.f ? da : 0.f) + (db > 0.f ? db : 0.f);
      }
#pragma unroll
      for (int j = 0; j < 8; ++j) {
        float da = gnb[8 + j] - bf2f(a1[j]);
        float db = gnb[8 + j] - bf2f(b1v[j]);
        tac[8 + j] += (da > 0.f ? da : 0.f) + (db > 0.f ? db : 0.f);
      }
    }
    if (i < dgv) {
      int ca = colS[rp + i];
      u16x8 a0 = *(const u16x8*)(g + (long)ca * 128 + d0);
      u16x8 a1 = *(const u16x8*)(g + (long)ca * 128 + d0 + 8);
#pragma unroll
      for (int j = 0; j < 8; ++j) {
        float da = gnb[j] - bf2f(a0[j]);
        tac[j] += (da > 0.f ? da : 0.f);
      }
#pragma unroll
      for (int j = 0; j < 8; ++j) {
        float da = gnb[8 + j] - bf2f(a1[j]);
        tac[8 + j] += (da > 0.f ? da : 0.f);
      }
    }
    // write T (bf16) into sT, swizzled 16B chunks
    union { int4 v; short s[8]; } p0, p1;
#pragma unroll
    for (int j = 0; j < 8; ++j) { p0.s[j] = f2bf(tac[j]); p1.s[j] = f2bf(tac[8 + j]); }
    *(int4*)(sT + swzB(gi, d0 * 2, 256))      = p0.v;
    *(int4*)(sT + swzB(gi, d0 * 2 + 16, 256)) = p1.v;
  }

  // ---- h A-fragments direct from global (overlap with barrier wait) ----
  const int node = nb + r0 + lr;
  const bool ok = node < nN;
  const int ndd = ok ? node : 0;
  bf16x8 afr[8];
  {
    const float* hr = h + (long)ndd * 128;
#pragma unroll
    for (int kk = 0; kk < 4; ++kk) {
      int k0 = kk * 32 + grp * 8;
      f32x4 a0 = *(const f32x4*)(hr + k0), a1 = *(const f32x4*)(hr + k0 + 4);
      union { bf16x8 v; short s[8]; } u;
      u.s[0] = f2bf(a0.x); u.s[1] = f2bf(a0.y); u.s[2] = f2bf(a0.z); u.s[3] = f2bf(a0.w);
      u.s[4] = f2bf(a1.x); u.s[5] = f2bf(a1.y); u.s[6] = f2bf(a1.z); u.s[7] = f2bf(a1.w);
      if (!ok) u.v = (bf16x8)(__bf16)0.f;
      afr[kk] = u.v;
    }
  }
  __syncthreads();   // W1 staged + T written

  // ---- T A-fragments from sT (rows of this wave pair) ----
#pragma unroll
  for (int kk = 0; kk < 4; ++kk) {
    afr[4 + kk] = *(const bf16x8*)(sT + swzB(r0 + lr, (kk * 32 + grp * 8) * 2, 256));
  }
  __syncthreads();   // all T reads done before relu overwrites sT

  // ---- layer 1: wave tile 16 rows x 64 cols, K=256 ----
  f32x4 acc[4];
#pragma unroll
  for (int j = 0; j < 4; ++j) acc[j] = (f32x4){0.f, 0.f, 0.f, 0.f};
#pragma unroll
  for (int kk = 0; kk < 8; ++kk) {
    int kB = (kk * 32 + grp * 8) * 2;
#pragma unroll
    for (int j = 0; j < 4; ++j) {
      bf16x8 b = *(const bf16x8*)(sW1 + swzB(cb + j * 16 + lr, kB, 512));
      acc[j] = __builtin_amdgcn_mfma_f32_16x16x32_bf16(afr[kk], b, acc[j], 0, 0, 0);
    }
  }
  float degs[4];
#pragma unroll
  for (int r = 0; r < 4; ++r) {
    int nn = nb + r0 + grp * 4 + r;
    degs[r] = (float)deg[nn];            // deg zeroed through NP
  }
#pragma unroll
  for (int j = 0; j < 4; ++j) {
    int col = cb + j * 16 + lr;
    float bv = b1[col];
    float c0v = c0[col];
#pragma unroll
    for (int r = 0; r < 4; ++r) {
      int row = r0 + grp * 4 + r;
      float v = acc[j][r] + bv + degs[r] * c0v;
      v = v > 0.f ? v : 0.f;
      *(short*)(sT + swzB(row, col * 2, 256)) = f2bf(v);
    }
  }
  __syncthreads();

  // ---- layer 2: A from sT, B direct from global NW2t (L1/L2-resident) ----
  f32x4 acc2[4];
#pragma unroll
  for (int j = 0; j < 4; ++j) acc2[j] = (f32x4){0.f, 0.f, 0.f, 0.f};
#pragma unroll
  for (int kk = 0; kk < 4; ++kk) {
    int kB = (kk * 32 + grp * 8) * 2;
    bf16x8 a = *(const bf16x8*)(sT + swzB(r0 + lr, kB, 256));
#pragma unroll
    for (int j = 0; j < 4; ++j) {
      bf16x8 b = *(const bf16x8*)(NW2t + (cb + j * 16 + lr) * 128 + kk * 32 + grp * 8);
      acc2[j] = __builtin_amdgcn_mfma_f32_16x16x32_bf16(a, b, acc2[j], 0, 0, 0);
    }
  }
#pragma unroll
  for (int j = 0; j < 4; ++j) {
    int col = cb + j * 16 + lr;
    float bv = b2[col];
#pragma unroll
    for (int r = 0; r < 4; ++r) {
      int nn = nb + r0 + grp * 4 + r;
      if (nn < nN) out[(long)nn * 128 + col] = acc2[j][r] + bv;
    }
  }
}

// ========================================================================
// ================= minimal fallback (per-edge atomics, 160KB ws) ========
// ========================================================================
__global__ void prep_kernel_fb(const float* __restrict__ ew1, const float* __restrict__ ew2,
                               const float* __restrict__ nw1, const float* __restrict__ nw2,
                               short* __restrict__ wsS) {
  int idx = blockIdx.x * 256 + threadIdx.x;
  if (idx < 16384) {
    int n = idx >> 7, k = idx & 127;
    wsS[idx] = f2bf(ew1[k * 128 + n]);
  } else if (idx < 32768) {
    int o = idx - 16384; int n = o >> 7, k = o & 127;
    wsS[idx] = f2bf(ew2[k * 128 + n]);
  } else if (idx < 65536) {
    int o = idx - 32768; int n = o >> 8, k = o & 255;
    wsS[idx] = f2bf(nw1[k * 128 + n]);
  } else if (idx < 81920) {
    int o = idx - 65536; int n = o >> 7, k = o & 127;
    wsS[idx] = f2bf(nw2[k * 128 + n]);
  }
}

__global__ __launch_bounds__(512) void edge_kernel_fb(
    const float* __restrict__ h, const int* __restrict__ ei,
    const float* __restrict__ b1, const float* __restrict__ b2,
    const short* __restrict__ W1t, const short* __restrict__ W2t,
    float* __restrict__ agg, int nE) {
  __shared__ __align__(16) char sW1[32768];
  __shared__ __align__(16) char sW2[32768];
  __shared__ __align__(16) char sT[32768];

  const int tid = threadIdx.x;
  const int lane = tid & 63, wv = tid >> 6;
  const int lr = lane & 15, grp = lane >> 4;
  const int eb = blockIdx.x * 128;
  const int* rowI = ei;
  const int* colI = ei + nE;

#pragma unroll
  for (int i = 0; i < 4; ++i) {
    int c = i * 512 + tid;
    int n = c >> 4, kB = (c & 15) * 16;
    *(int4*)(sW1 + swzB(n, kB, 256)) = ((const int4*)W1t)[c];
    *(int4*)(sW2 + swzB(n, kB, 256)) = ((const int4*)W2t)[c];
  }
  bf16x8 afr[4];
  {
    int slot = eb + wv * 16 + lr;
    int r = 0, cc = 0;
    if (slot < nE) { r = rowI[slot]; cc = colI[slot]; }
    const float* hr = h + (long)r * 128;
    const float* hc = h + (long)cc * 128;
#pragma unroll
    for (int kk = 0; kk < 4; ++kk) {
      int k0 = kk * 32 + grp * 8;
      f32x4 a0 = *(const f32x4*)(hr + k0), a1 = *(const f32x4*)(hr + k0 + 4);
      f32x4 c0_ = *(const f32x4*)(hc + k0), c1 = *(const f32x4*)(hc + k0 + 4);
      union { bf16x8 v; short s[8]; } u;
      u.s[0] = f2bf(a0.x - c0_.x); u.s[1] = f2bf(a0.y - c0_.y);
      u.s[2] = f2bf(a0.z - c0_.z); u.s[3] = f2bf(a0.w - c0_.w);
      u.s[4] = f2bf(a1.x - c1.x); u.s[5] = f2bf(a1.y - c1.y);
      u.s[6] = f2bf(a1.z - c1.z); u.s[7] = f2bf(a1.w - c1.w);
      afr[kk] = u.v;
    }
  }
  __syncthreads();

  f32x4 acc[8];
#pragma unroll
  for (int j = 0; j < 8; ++j) acc[j] = (f32x4){0.f, 0.f, 0.f, 0.f};
#pragma unroll
  for (int kk = 0; kk < 4; ++kk) {
    int kB = (kk * 32 + grp * 8) * 2;
#pragma unroll
    for (int j = 0; j < 8; ++j) {
      bf16x8 b = *(const bf16x8*)(sW1 + swzB(j * 16 + lr, kB, 256));
      acc[j] = __builtin_amdgcn_mfma_f32_16x16x32_bf16(afr[kk], b, acc[j], 0, 0, 0);
    }
  }
#pragma unroll
  for (int j = 0; j < 8; ++j) {
    int col = j * 16 + lr;
    float bv = b1[col];
#pragma unroll
    for (int r = 0; r < 4; ++r) {
      int row = wv * 16 + grp * 4 + r;
      float v = acc[j][r] + bv;
      v = v > 0.f ? v : 0.f;
      *(short*)(sT + swzB(row, col * 2, 256)) = f2bf(v);
    }
  }
  __syncthreads();

  f32x4 acc2[8];
#pragma unroll
  for (int j = 0; j < 8; ++j) acc2[j] = (f32x4){0.f, 0.f, 0.f, 0.f};
#pragma unroll
  for (int kk = 0; kk < 4; ++kk) {
    int kB = (kk * 32 + grp * 8) * 2;
    bf16x8 a = *(const bf16x8*)(sT + swzB(wv * 16 + lr, kB, 256));
#pragma unroll
    for (int j = 0; j < 8; ++j) {
      bf16x8 b = *(const bf16x8*)(sW2 + swzB(j * 16 + lr, kB, 256));
      acc2[j] = __builtin_amdgcn_mfma_f32_16x16x32_bf16(a, b, acc2[j], 0, 0, 0);
    }
  }
  int nd[4]; bool okr[4];
#pragma unroll
  for (int r = 0; r < 4; ++r) {
    int e = eb + wv * 16 + grp * 4 + r;
    okr[r] = e < nE;
    nd[r] = okr[r] ? rowI[e] : 0;
  }
#pragma unroll
  for (int j = 0; j < 8; ++j) {
    int col = j * 16 + lr;
    float bv = b2[col];
#pragma unroll
    for (int r = 0; r < 4; ++r) {
      if (okr[r]) atomicAdd(agg + (long)nd[r] * 128 + col, acc2[j][r] + bv);
    }
  }
}

__global__ __launch_bounds__(512) void node_kernel_fb(
    const float* __restrict__ h, const float* agg,
    const float* __restrict__ b1, const float* __restrict__ b2,
    const short* __restrict__ W1t, const short* __restrict__ W2t,
    float* out, int nN) {
  __shared__ __align__(16) char sZ[32768];
  __shared__ __align__(16) char sW1[65536];
  __shared__ __align__(16) char sW2[32768];
  __shared__ __align__(16) char sT[16384];

  const int tid = threadIdx.x;
  const int lane = tid & 63, wv = tid >> 6;
  const int lr = lane & 15, grp = lane >> 4;
  const int nb = blockIdx.x * 64;

#pragma unroll
  for (int i = 0; i < 8; ++i) {
    int c = i * 512 + tid;
    int n = c >> 5, kB = (c & 31) * 16;
    *(int4*)(sW1 + swzB(n, kB, 512)) = ((const int4*)W1t)[c];
  }
#pragma unroll
  for (int i = 0; i < 4; ++i) {
    int c = i * 512 + tid;
    int n = c >> 4, kB = (c & 15) * 16;
    *(int4*)(sW2 + swzB(n, kB, 256)) = ((const int4*)W2t)[c];
  }
  {
    int i = tid >> 3;
    int node = nb + i;
    bool ok = node < nN;
    int nd = ok ? node : 0;
#pragma unroll
    for (int it = 0; it < 8; ++it) {
      int c4 = (tid & 7) + it * 8;
      int col = c4 * 4;
      f32x4 v;
      if (col < 128) v = *(const f32x4*)(h + (long)nd * 128 + col);
      else           v = *(const f32x4*)(agg + (long)nd * 128 + (col - 128));
      if (!ok) v = (f32x4){0.f, 0.f, 0.f, 0.f};
      s16x4 p;
      p.x = f2bf(v.x); p.y = f2bf(v.y); p.z = f2bf(v.z); p.w = f2bf(v.w);
      *(s16x4*)(sZ + swzB(i, col * 2, 512)) = p;
    }
  }
  __syncthreads();

  const int r0 = (wv >> 1) * 16;
  const int cb = (wv & 1) * 64;
  f32x4 acc[4];
#pragma unroll
  for (int j = 0; j < 4; ++j) acc[j] = (f32x4){0.f, 0.f, 0.f, 0.f};
#pragma unroll
  for (int kk = 0; kk < 8; ++kk) {
    int kB = (kk * 32 + grp * 8) * 2;
    bf16x8 a = *(const bf16x8*)(sZ + swzB(r0 + lr, kB, 512));
#pragma unroll
    for (int j = 0; j < 4; ++j) {
      bf16x8 b = *(const bf16x8*)(sW1 + swzB(cb + j * 16 + lr, kB, 512));
      acc[j] = __builtin_amdgcn_mfma_f32_16x16x32_bf16(a, b, acc[j], 0, 0, 0);
    }
  }
#pragma unroll
  for (int j = 0; j < 4; ++j) {
    int col = cb + j * 16 + lr;
    float bv = b1[col];
#pragma unroll
    for (int r = 0; r < 4; ++r) {
      int row = r0 + grp * 4 + r;
      float v = acc[j][r] + bv;
      v = v > 0.f ? v : 0.f;
      *(short*)(sT + swzB(row, col * 2, 256)) = f2bf(v);
    }
  }
  __syncthreads();

  f32x4 acc2[4];
#pragma unroll
  for (int j = 0; j < 4; ++j) acc2[j] = (f32x4){0.f, 0.f, 0.f, 0.f};
#pragma unroll
  for (int kk = 0; kk < 4; ++kk) {
    int kB = (kk * 32 + grp * 8) * 2;
    bf16x8 a = *(const bf16x8*)(sT + swzB(r0 + lr, kB, 256));
#pragma unroll
    for (int j = 0; j < 4; ++j) {
      bf16x8 b = *(const bf16x8*)(sW2 + swzB(cb + j * 16 + lr, kB, 256));
      acc2[j] = __builtin_amdgcn_mfma_f32_16x16x32_bf16(a, b, acc2[j], 0, 0, 0);
    }
  }
#pragma unroll
  for (int j = 0; j < 4; ++j) {
    int col = cb + j * 16 + lr;
    float bv = b2[col];
#pragma unroll
    for (int r = 0; r < 4; ++r) {
      int node = nb + r0 + grp * 4 + r;
      if (node < nN) out[(long)node * 128 + col] = acc2[j][r] + bv;
    }
  }
}

// ========================================================================
extern "C" void kernel_launch(void* const* d_in, const int* in_sizes, int n_in,
                              void* d_out, int out_size, void* d_ws, size_t ws_size,
                              hipStream_t stream) {
  const float* h   = (const float*)d_in[0];
  const int*   ei  = (const int*)d_in[1];
  const float* ew1 = (const float*)d_in[2];
  const float* eb1 = (const float*)d_in[3];
  const float* ew2 = (const float*)d_in[4];
  const float* eb2 = (const float*)d_in[5];
  const float* nw1 = (const float*)d_in[6];
  const float* nb1 = (const float*)d_in[7];
  const float* nw2 = (const float*)d_in[8];
  const float* nb2 = (const float*)d_in[9];
  float* out = (float*)d_out;

  const int E = in_sizes[1] / 2;            // 600000
  const int N = in_sizes[0] / 128;          // 50000
  const int NP = ((N + 255) / 256) * 256;   // 50176
  const int NB = NP / 256;                  // 196
  const int degInt4 = NP / 4;

  // ---- ws layout ----
  char* base = (char*)d_ws;
  short* W1t    = (short*)base;                    // 16384 bf16
  short* NW1t   = W1t + 16384;                     // 32768
  short* NW2t   = NW1t + 32768;                    // 16384
  float* c0     = (float*)(NW2t + 16384);          // 128
  int*   deg    = (int*)(c0 + 128);                // NP
  int*   cursor = deg + NP;                        // NP
  int*   rowptr = cursor + NP;                     // NP
  int*   bsums  = rowptr + NP;                     // 256
  int*   colS   = bsums + 256;                     // E
  size_t off    = (((size_t)((char*)(colS + E) - base)) + 15) & ~(size_t)15;
  unsigned short* g = (unsigned short*)(base + off);        // NP*128 bf16
  size_t needed = off + (size_t)NP * 256;

  if (ws_size >= needed) {
    const int gBlocks = (N + 63) / 64;
    const int histBlocks = (E + 255) / 256;
    int prepBlocks = (65664 + degInt4 + 255) / 256;
    prep_all<<<prepBlocks, 256, 0, stream>>>(ew1, ew2, eb2, nw1, nw2,
                                             W1t, NW1t, NW2t, c0, deg, degInt4);
    gh_kernel<<<gBlocks + histBlocks, 256, 0, stream>>>(h, W1t, g, N, ei, deg, E, gBlocks);
    scan_local_kernel<<<NB, 256, 0, stream>>>(deg, cursor, bsums);
    finalize_scan_kernel<<<NB, 256, 0, stream>>>(cursor, bsums, rowptr, NB);
    scatter2_kernel<<<(E + 255) / 256, 256, 0, stream>>>(ei, cursor, colS, E);
    agg_node_kernel<<<(N + 63) / 64, 512, 0, stream>>>(h, g, rowptr, deg, colS, eb1,
                                                       nb1, nb2, NW1t, NW2t, c0, out, N);
    return;
  }

  // ---- fallback: per-edge atomics (needs only 160KB ws) ----
  short* wsS   = (short*)d_ws;
  short* fW1t  = wsS;
  short* fW2t  = wsS + 16384;
  short* fNW1t = wsS + 32768;
  short* fNW2t = wsS + 65536;
  hipMemsetAsync(d_out, 0, (size_t)out_size * sizeof(float), stream);
  prep_kernel_fb<<<320, 256, 0, stream>>>(ew1, ew2, nw1, nw2, wsS);
  edge_kernel_fb<<<(E + 127) / 128, 512, 0, stream>>>(h, ei, eb1, eb2, fW1t, fW2t, out, E);
  node_kernel_fb<<<(N + 63) / 64, 512, 0, stream>>>(h, out, nb1, nb2, fNW1t, fNW2t, out, N);
}